// Round 12
// baseline (832.807 us; speedup 1.0000x reference)
//
#include <hip/hip_runtime.h>
#include <hip/hip_bf16.h>

// B=8, S=2048, D=1024, fp32 in/out.
static constexpr int S = 2048;
static constexpr int D = 1024;
static constexpr int NB = 8;

#define LOG2E 1.4426950408889634f

typedef float  f32x4  __attribute__((ext_vector_type(4)));
typedef __bf16 bf16x4 __attribute__((ext_vector_type(4)));
typedef __bf16 bf16x8 __attribute__((ext_vector_type(8)));

#define CM_F32    0
#define CM_SPLIT  1
#define CM_TRANSV 2

#define GLD16(g, l) __builtin_amdgcn_global_load_lds(                         \
    (const __attribute__((address_space(1))) void*)(g),                       \
    (__attribute__((address_space(3))) void*)(l), 16, 0, 0)

#define MFMA16(a, b, c) __builtin_amdgcn_mfma_f32_16x16x32_bf16((a), (b), (c), 0, 0, 0)
#define BAR() __builtin_amdgcn_s_barrier()
#define PRIO1() __builtin_amdgcn_s_setprio(1)
#define PRIO0() __builtin_amdgcn_s_setprio(0)
#define WAIT_LGKM(n) asm volatile("s_waitcnt lgkmcnt(" #n ")" ::: "memory")
#define WAIT_VM(n)   asm volatile("s_waitcnt vmcnt(" #n ")" ::: "memory")

// ---------------------------------------------------------------------------
// r10 structure (6-phase never-drain counted pipeline, 16x16x32 MFMA,
// plane-separated LDS, 4-slot XOR swizzle) with all per-call address
// arithmetic eliminated:
//  - K-loop unrolled by 2: buf is a literal -> LDS addresses fold to
//    base + compile-time offset (ds_read immediate).
//  - Global staging uses 8 named running pointers advanced by a constant
//    stride per tile (no row/chunk math, no 64-bit recompute).
//  - LDS read slot-XOR collapses to per-thread constant:
//    slot = fq ^ ((fr>>1)&3); read addr = base + buf*BUFSZ + p*PLANE + i*1024.
// Waits/barriers identical to r10 (verified passing):
//  T3 (BNT=256): 6 phases; lgkm(4) at P0,P1,P2,P4; lgkm(0)@P5 before BAR;
//    vm(2)@P1 (retire t's lo), vm(4)@P5 (retire t+1's hi); vm(0) only edges.
//  T1 (BNT=128): 2 phases; vm(3)+BAR seals; lgkm(8)/lgkm(0).
// XCD-bijective block swizzle (T1/m204) kept (FETCH 135->49 MB).
// ---------------------------------------------------------------------------
template <int TERMS, int CMODE, int BNT>
__global__ __launch_bounds__(512, 1) void bgemm256(
    const __bf16* __restrict__ Ah_, const __bf16* __restrict__ Al_, long sAz,
    const __bf16* __restrict__ Bh_, const __bf16* __restrict__ Bl_, long sBz,
    int lda, int ldb,
    void* __restrict__ C1, void* __restrict__ C2, int ldc, long sCz,
    const float* __restrict__ bias, int K)
{
    extern __shared__ char smem[];
    constexpr int NW_N  = BNT / 64;
    constexpr int NW_M  = 8 / NW_N;
    constexpr int WM    = 256 / NW_M;
    constexpr int MI    = WM / 16;
    constexpr int APLANE = 16384;            // 256 rows x 64 B
    constexpr int BPLANE = BNT * 64;
    constexpr int BOFF   = 2 * APLANE;
    constexpr int BUFSZ  = 2 * APLANE + 2 * BPLANE;
    constexpr int ASTR   = (TERMS == 3) ? 32 : 64;   // k-elems per tile

    // ---- XCD-aware bijective block swizzle (T1, m204) ----
    int bx, by, bz;
    {
        const int gx = gridDim.x, gy = gridDim.y;
        const int nwg = gx * gy * gridDim.z;
        const int wg = blockIdx.x + gx * (blockIdx.y + gy * blockIdx.z);
        const int q = nwg >> 3, r = nwg & 7;
        const int xcd = wg & 7, i = wg >> 3;
        const int nid = (xcd < r) ? xcd * (q + 1) + i
                                  : r * (q + 1) + (xcd - r) * q + i;
        bx = nid % gx;
        const int tmp = nid / gx;
        by = tmp % gy;
        bz = tmp / gy;
    }

    const int t = threadIdx.x;
    const int z = bz;
    const int m0 = by * 256;
    const int n0 = bx * BNT;
    const int lane = t & 63, wid = t >> 6;
    const int wr = wid / NW_N, wc = wid % NW_N;
    const int fr = lane & 15, fq = lane >> 4;
    const int lrow = lane >> 2, lslot = lane & 3;
    const int schunk = lslot ^ ((lrow >> 1) & 3);   // stage source chunk

    const __bf16* Ahz = Ah_ + (long)z * sAz;
    const __bf16* Alz = (TERMS == 3) ? Al_ + (long)z * sAz : nullptr;
    const __bf16* Bhz = Bh_ + (long)z * sBz;
    const __bf16* Blz = (TERMS == 3) ? Bl_ + (long)z * sBz : nullptr;

    // ---- precomputed LDS bases ----
    const int slotR = fq ^ ((fr >> 1) & 3);
    char* const sRdA = smem + (wr * WM + fr) * 64 + slotR * 16;
    char* const sRdB = smem + BOFF + (wc * 64 + fr) * 64 + slotR * 16;
    char* const sStA = smem + wid * 2048;
    char* const sStB = smem + BOFF + ((TERMS == 3) ? wid * 2048 : wid * 1024);

    // ---- running global stage pointers (advance by ASTR per tile) ----
    const int arow0 = m0 + wid * 32 + lrow, arow1 = arow0 + 16;
    const __bf16 *pA00, *pA01, *pA10, *pA11;
    if constexpr (TERMS == 3) {
        pA00 = Ahz + (long)arow0 * lda + schunk * 8;
        pA01 = Ahz + (long)arow1 * lda + schunk * 8;
        pA10 = Alz + (long)arow0 * lda + schunk * 8;
        pA11 = Alz + (long)arow1 * lda + schunk * 8;
    } else {
        pA00 = Ahz + (long)arow0 * lda + schunk * 8;
        pA01 = Ahz + (long)arow1 * lda + schunk * 8;
        pA10 = Ahz + (long)arow0 * lda + 32 + schunk * 8;
        pA11 = Ahz + (long)arow1 * lda + 32 + schunk * 8;
    }
    const __bf16 *pB00, *pB01, *pB10, *pB11;
    if constexpr (TERMS == 3) {
        const int brow0 = n0 + wid * 32 + lrow, brow1 = brow0 + 16;
        pB00 = Bhz + (long)brow0 * ldb + schunk * 8;
        pB01 = Bhz + (long)brow1 * ldb + schunk * 8;
        pB10 = Blz + (long)brow0 * ldb + schunk * 8;
        pB11 = Blz + (long)brow1 * ldb + schunk * 8;
    } else {
        const int brow = n0 + wid * 16 + lrow;
        pB00 = Bhz + (long)brow * ldb + schunk * 8;
        pB10 = Bhz + (long)brow * ldb + 32 + schunk * 8;
        pB01 = pB11 = nullptr;
    }

    auto stgA = [&](int tb, int p) {   // tb, p: literal at call sites
        char* d = sStA + tb * BUFSZ + p * APLANE;
        if (p == 0) { GLD16(pA00, d); GLD16(pA01, d + 1024); pA00 += ASTR; pA01 += ASTR; }
        else        { GLD16(pA10, d); GLD16(pA11, d + 1024); pA10 += ASTR; pA11 += ASTR; }
    };
    auto stgB = [&](int tb, int p) {
        char* d = sStB + tb * BUFSZ + p * BPLANE;
        if constexpr (TERMS == 3) {
            if (p == 0) { GLD16(pB00, d); GLD16(pB01, d + 1024); pB00 += ASTR; pB01 += ASTR; }
            else        { GLD16(pB10, d); GLD16(pB11, d + 1024); pB10 += ASTR; pB11 += ASTR; }
        } else {
            if (p == 0) { GLD16(pB00, d); pB00 += ASTR; }
            else        { GLD16(pB10, d); pB10 += ASTR; }
        }
    };
    auto rdA = [&](int buf, int p, int mi) -> bf16x8 {
        return *(const bf16x8*)(sRdA + buf * BUFSZ + p * APLANE + mi * 1024);
    };
    auto rdB = [&](int buf, int p, int ni) -> bf16x8 {
        return *(const bf16x8*)(sRdB + buf * BUFSZ + p * BPLANE + ni * 1024);
    };

    f32x4 acc[MI][4] = {};
    const int ktiles = K / ((TERMS == 3) ? 32 : 64);

    if constexpr (TERMS == 3) {
        bf16x8 b0[4], b1[4], aA[4], aB[4], aA2[4], aB2[4];
        auto mb = [&](int base, bf16x8 (&A)[4], bf16x8 (&B)[4]) {
#pragma unroll
            for (int mi = 0; mi < 4; ++mi)
#pragma unroll
                for (int ni = 0; ni < 4; ++ni)
                    acc[base + mi][ni] = MFMA16(A[mi], B[ni], acc[base + mi][ni]);
        };
        // prologue
        stgA(0, 0); stgB(0, 0); stgA(0, 1); stgB(0, 1);
        WAIT_VM(0);
        BAR();
#pragma unroll
        for (int ni = 0; ni < 4; ++ni) b0[ni] = rdB(0, 0, ni);
#pragma unroll
        for (int mi = 0; mi < 4; ++mi) aA[mi] = rdA(0, 0, mi);
#pragma unroll
        for (int mi = 0; mi < 4; ++mi) aB[mi] = rdA(0, 0, 4 + mi);

#define TILE3(BUF, NBUF, TT)                                                   \
        {                                                                      \
            const bool pf = ((TT) + 1 < ktiles);                               \
            /* P0 */                                                           \
            if (pf) stgA(NBUF, 0);                                             \
            BAR(); WAIT_LGKM(4);                                               \
            PRIO1(); mb(0, aA, b0); PRIO0(); BAR();                            \
            /* P1 */                                                           \
            if (pf) { WAIT_VM(2); stgB(NBUF, 0); } else { WAIT_VM(0); }        \
            BAR();                                                             \
            _Pragma("unroll")                                                  \
            for (int ni = 0; ni < 4; ++ni) b1[ni] = rdB(BUF, 1, ni);           \
            WAIT_LGKM(4);                                                      \
            PRIO1(); mb(4, aB, b0); PRIO0(); BAR();                            \
            /* P2 */                                                           \
            _Pragma("unroll")                                                  \
            for (int mi = 0; mi < 4; ++mi) aA2[mi] = rdA(BUF, 1, mi);          \
            if (pf) stgA(NBUF, 1);                                             \
            BAR(); WAIT_LGKM(4);                                               \
            PRIO1(); mb(0, aA, b1); PRIO0(); BAR();                            \
            /* P3 */                                                           \
            _Pragma("unroll")                                                  \
            for (int mi = 0; mi < 4; ++mi) aB2[mi] = rdA(BUF, 1, 4 + mi);      \
            if (pf) stgB(NBUF, 1);                                             \
            BAR();                                                             \
            PRIO1(); mb(4, aB, b1); PRIO0(); BAR();                            \
            /* P4 */                                                           \
            WAIT_LGKM(4);                                                      \
            PRIO1(); mb(0, aA2, b0); PRIO0(); BAR();                           \
            /* P5 */                                                           \
            if (pf) WAIT_VM(4);                                                \
            WAIT_LGKM(0);                                                      \
            BAR();                                                             \
            PRIO1(); mb(4, aB2, b0); PRIO0();                                  \
            if (pf) {                                                          \
                _Pragma("unroll")                                              \
                for (int ni = 0; ni < 4; ++ni) b0[ni] = rdB(NBUF, 0, ni);      \
                _Pragma("unroll")                                              \
                for (int mi = 0; mi < 4; ++mi) aA[mi] = rdA(NBUF, 0, mi);      \
                _Pragma("unroll")                                              \
                for (int mi = 0; mi < 4; ++mi) aB[mi] = rdA(NBUF, 0, 4 + mi);  \
            }                                                                  \
        }

        for (int tt = 0; tt < ktiles; tt += 2) {
            TILE3(0, 1, tt);
            TILE3(1, 0, tt + 1);
        }
#undef TILE3
    } else {  // TERMS == 1 (PV, BNT=128, MI=4)
        bf16x8 b0[4], b1[4], a0[4], a1[4];
        auto mb = [&](bf16x8 (&A)[4], bf16x8 (&B)[4]) {
#pragma unroll
            for (int mi = 0; mi < 4; ++mi)
#pragma unroll
                for (int ni = 0; ni < 4; ++ni)
                    acc[mi][ni] = MFMA16(A[mi], B[ni], acc[mi][ni]);
        };
        stgA(0, 0); stgB(0, 0); stgA(0, 1); stgB(0, 1);
        WAIT_VM(0);
        BAR();
#pragma unroll
        for (int ni = 0; ni < 4; ++ni) b0[ni] = rdB(0, 0, ni);
#pragma unroll
        for (int mi = 0; mi < 4; ++mi) a0[mi] = rdA(0, 0, mi);

#define TILE1(BUF, NBUF, TT)                                                   \
        {                                                                      \
            const bool pf = ((TT) + 1 < ktiles);                               \
            /* P0 */                                                           \
            if (pf) { stgA(NBUF, 0); stgB(NBUF, 0); WAIT_VM(3); }              \
            else    { WAIT_VM(0); }                                            \
            BAR();                                                             \
            _Pragma("unroll")                                                  \
            for (int ni = 0; ni < 4; ++ni) b1[ni] = rdB(BUF, 1, ni);           \
            _Pragma("unroll")                                                  \
            for (int mi = 0; mi < 4; ++mi) a1[mi] = rdA(BUF, 1, mi);           \
            WAIT_LGKM(8);                                                      \
            PRIO1(); mb(a0, b0); PRIO0(); BAR();                               \
            /* P1 */                                                           \
            if (pf) { stgA(NBUF, 1); stgB(NBUF, 1); WAIT_VM(3); }              \
            WAIT_LGKM(0);                                                      \
            BAR();                                                             \
            PRIO1(); mb(a1, b1); PRIO0();                                      \
            if (pf) {                                                          \
                _Pragma("unroll")                                              \
                for (int ni = 0; ni < 4; ++ni) b0[ni] = rdB(NBUF, 0, ni);      \
                _Pragma("unroll")                                              \
                for (int mi = 0; mi < 4; ++mi) a0[mi] = rdA(NBUF, 0, mi);      \
            }                                                                  \
        }

        for (int tt = 0; tt < ktiles; tt += 2) {
            TILE1(0, 1, tt);
            TILE1(1, 0, tt + 1);
        }
#undef TILE1
    }

    // ---------------- epilogue ----------------
#pragma unroll
    for (int mi = 0; mi < MI; ++mi) {
        const int rbase = m0 + wr * WM + mi * 16 + fq * 4;
#pragma unroll
        for (int ni = 0; ni < 4; ++ni) {
            const int col = n0 + wc * 64 + ni * 16 + fr;
            f32x4 a = acc[mi][ni];
            if (CMODE != CM_F32) {
                const float bv = bias[col];
#pragma unroll
                for (int j = 0; j < 4; ++j) a[j] += bv;
            }
            if (CMODE == CM_F32) {
                float* C = (float*)C1 + (long)z * sCz;
#pragma unroll
                for (int j = 0; j < 4; ++j)
                    C[(long)(rbase + j) * ldc + col] = a[j];
            } else if (CMODE == CM_SPLIT) {
                __bf16* Ch = (__bf16*)C1;
                __bf16* Cl = (__bf16*)C2;
#pragma unroll
                for (int j = 0; j < 4; ++j) {
                    const float q = a[j];
                    const __bf16 h = (__bf16)q;
                    Ch[(long)(rbase + j) * ldc + col] = h;
                    Cl[(long)(rbase + j) * ldc + col] = (__bf16)(q - (float)h);
                }
            } else {  // CM_TRANSV: Vt[b][col][s] bf16
                const int b_ = rbase >> 11;
                const int s_ = rbase & (S - 1);
                bf16x4 h;
#pragma unroll
                for (int j = 0; j < 4; ++j) h[j] = (__bf16)a[j];
                *(bf16x4*)((__bf16*)C1 + ((long)b_ * D + col) * S + s_) = h;
            }
        }
    }
}

// ---------------------------------------------------------------------------
__global__ __launch_bounds__(256) void xsplit(
    const float* __restrict__ X, __bf16* __restrict__ Xh, __bf16* __restrict__ Xl)
{
    const long i = ((long)blockIdx.x * 256 + threadIdx.x) * 4;
    f32x4 v = *(const f32x4*)(X + i);
    bf16x4 h, l;
#pragma unroll
    for (int j = 0; j < 4; ++j) {
        h[j] = (__bf16)v[j];
        l[j] = (__bf16)(v[j] - (float)h[j]);
    }
    *(bf16x4*)(Xh + i) = h;
    *(bf16x4*)(Xl + i) = l;
}

// ---------------------------------------------------------------------------
__global__ void wsplit(const float* __restrict__ W0, const float* __restrict__ W1,
                       const float* __restrict__ W2,
                       __bf16* __restrict__ Th, __bf16* __restrict__ Tl)
{
    const float* W = blockIdx.z == 0 ? W0 : (blockIdx.z == 1 ? W1 : W2);
    __bf16* th = Th + (long)blockIdx.z * 1024 * 1024;
    __bf16* tl = Tl + (long)blockIdx.z * 1024 * 1024;
    __shared__ float tile[32][33];
    const int bx = blockIdx.x * 32, by = blockIdx.y * 32;
    const int tx = threadIdx.x, ty = threadIdx.y;
#pragma unroll
    for (int i = ty; i < 32; i += 8) tile[i][tx] = W[(long)(by + i) * 1024 + bx + tx];
    __syncthreads();
#pragma unroll
    for (int i = ty; i < 32; i += 8) {
        const float v = tile[tx][i];
        const __bf16 h = (__bf16)v;
        th[(long)(bx + i) * 1024 + by + tx] = h;
        tl[(long)(bx + i) * 1024 + by + tx] = (__bf16)(v - (float)h);
    }
}

// ---------------------------------------------------------------------------
// Fused row softmax: read f32 score row, write P = exp(s-m)/l as bf16
// IN-PLACE into the start of the row's f32 storage.
// ---------------------------------------------------------------------------
__global__ __launch_bounds__(256) void pconv(float* __restrict__ Sb)
{
    const long row = blockIdx.x;
    float* p = Sb + row * (long)S;
    const int t = threadIdx.x;

    f32x4 x0 = *(const f32x4*)(p + t * 8);
    f32x4 x1 = *(const f32x4*)(p + t * 8 + 4);

    float m = -3.4e38f;
#pragma unroll
    for (int j = 0; j < 4; ++j) m = fmaxf(m, fmaxf(x0[j], x1[j]));
#pragma unroll
    for (int o = 32; o >= 1; o >>= 1) m = fmaxf(m, __shfl_xor(m, o));

    __shared__ float wm[4], wsum[4];
    const int wid = t >> 6, lane = t & 63;
    if (lane == 0) wm[wid] = m;
    __syncthreads();
    m = fmaxf(fmaxf(wm[0], wm[1]), fmaxf(wm[2], wm[3]));

    float e[8], ssum = 0.f;
#pragma unroll
    for (int j = 0; j < 4; ++j) {
        e[j]     = exp2f((x0[j] - m) * LOG2E);
        e[4 + j] = exp2f((x1[j] - m) * LOG2E);
        ssum += e[j] + e[4 + j];
    }
#pragma unroll
    for (int o = 32; o >= 1; o >>= 1) ssum += __shfl_xor(ssum, o);
    if (lane == 0) wsum[wid] = ssum;
    __syncthreads();
    const float invl = 1.0f / (wsum[0] + wsum[1] + wsum[2] + wsum[3]);

    bf16x8 outv;
#pragma unroll
    for (int j = 0; j < 8; ++j) outv[j] = (__bf16)(e[j] * invl);
    *(bf16x8*)((__bf16*)p + t * 8) = outv;
}

// ---------------------------------------------------------------------------
extern "C" void kernel_launch(void* const* d_in, const int* in_sizes, int n_in,
                              void* d_out, int out_size, void* d_ws, size_t ws_size,
                              hipStream_t stream)
{
    const float* X  = (const float*)d_in[0];
    const float* Wq = (const float*)d_in[1];
    const float* bq = (const float*)d_in[2];
    const float* Wk = (const float*)d_in[3];
    const float* bk = (const float*)d_in[4];
    const float* Wv = (const float*)d_in[5];
    const float* bv = (const float*)d_in[6];
    float* out = (float*)d_out;
    char* ws = (char*)d_ws;
    const size_t MB = 1u << 20;

    // layout (236 MB):
    // [0,6) Wth[3]  [6,12) Wtl[3]
    // [12,76) X region: Xh|Xl during projections; Sb f32 [4][S][S] after (P in-place)
    // [76,108) Qh  [108,140) Ql  [140,172) Kh  [172,204) Kl  [204,236) Vt bf16
    __bf16* Wth = (__bf16*)ws;          __bf16* Wtl = (__bf16*)(ws + 6 * MB);
    __bf16* Xh = (__bf16*)(ws + 12 * MB);  __bf16* Xl = (__bf16*)(ws + 44 * MB);
    __bf16* Qh = (__bf16*)(ws + 76 * MB);  __bf16* Ql = (__bf16*)(ws + 108 * MB);
    __bf16* Kh = (__bf16*)(ws + 140 * MB); __bf16* Kl = (__bf16*)(ws + 172 * MB);
    __bf16* Vt = (__bf16*)(ws + 204 * MB);
    float*  Sb = (float*)(ws + 12 * MB);   // [4][S][S] f32; P bf16 in-place

    const int LDS_T3 = 131072;             // 2 bufs x (2x16K A + 2x16K B)
    const int LDS_T1 = 98304;              // 2 bufs x (2x16K A + 2x8K B)
    hipFuncSetAttribute(reinterpret_cast<const void*>(&bgemm256<3, CM_SPLIT, 256>),
                        hipFuncAttributeMaxDynamicSharedMemorySize, LDS_T3);
    hipFuncSetAttribute(reinterpret_cast<const void*>(&bgemm256<3, CM_TRANSV, 256>),
                        hipFuncAttributeMaxDynamicSharedMemorySize, LDS_T3);
    hipFuncSetAttribute(reinterpret_cast<const void*>(&bgemm256<3, CM_F32, 256>),
                        hipFuncAttributeMaxDynamicSharedMemorySize, LDS_T3);
    hipFuncSetAttribute(reinterpret_cast<const void*>(&bgemm256<1, CM_F32, 128>),
                        hipFuncAttributeMaxDynamicSharedMemorySize, LDS_T1);

    // 1) split inputs to bf16 hi/lo planes
    xsplit<<<dim3(16384), 256, 0, stream>>>(X, Xh, Xl);
    wsplit<<<dim3(32, 32, 3), dim3(32, 8), 0, stream>>>(Wq, Wk, Wv, Wth, Wtl);

    // 2) projections (3-term split GEMM)
    const long MW = 1024 * 1024;
    bgemm256<3, CM_SPLIT, 256><<<dim3(D / 256, 64, 1), 512, LDS_T3, stream>>>(
        Xh, Xl, 0, Wth, Wtl, 0, D, D, Qh, Ql, D, 0, bq, D);
    bgemm256<3, CM_SPLIT, 256><<<dim3(D / 256, 64, 1), 512, LDS_T3, stream>>>(
        Xh, Xl, 0, Wth + MW, Wtl + MW, 0, D, D, Kh, Kl, D, 0, bk, D);
    bgemm256<3, CM_TRANSV, 256><<<dim3(D / 256, 64, 1), 512, LDS_T3, stream>>>(
        Xh, Xl, 0, Wth + 2 * MW, Wtl + 2 * MW, 0, D, D, Vt, nullptr, 0, 0, bv, D);

    // 3) per 4-batch group: scores -> in-place softmax->bf16 P -> PV
    for (int g = 0; g < 2; ++g) {
        const int b0 = g * 4;
        bgemm256<3, CM_F32, 256><<<dim3(S / 256, S / 256, 4), 512, LDS_T3, stream>>>(
            Qh + (long)b0 * S * D, Ql + (long)b0 * S * D, (long)S * D,
            Kh + (long)b0 * S * D, Kl + (long)b0 * S * D, (long)S * D,
            D, D, Sb, nullptr, S, (long)S * S, nullptr, D);
        pconv<<<dim3(4 * S), 256, 0, stream>>>(Sb);
        // PV: A = bf16 P rows embedded in f32 buffer (lda = 2S bf16 elements)
        bgemm256<1, CM_F32, 128><<<dim3(D / 128, S / 256, 4), 512, LDS_T1, stream>>>(
            (const __bf16*)Sb, nullptr, 2L * S * S,
            Vt + (long)b0 * D * S, nullptr, (long)D * S,
            2 * S, S, out + (long)b0 * S * D, nullptr, D, (long)S * D, nullptr, S);
    }
}

// Round 13
// 515.131 us; speedup vs baseline: 1.6167x; 1.6167x over previous
//
#include <hip/hip_runtime.h>
#include <hip/hip_bf16.h>

// B=8, S=2048, D=1024, fp32 in/out.
static constexpr int S = 2048;
static constexpr int D = 1024;
static constexpr int NB = 8;

#define LOG2E 1.4426950408889634f

typedef float    f32x4  __attribute__((ext_vector_type(4)));
typedef _Float16 f16x4  __attribute__((ext_vector_type(4)));
typedef _Float16 f16x8  __attribute__((ext_vector_type(8)));

#define CM_F32    0
#define CM_SPLIT  1
#define CM_TRANSV 2

#define GLD16(g, l) __builtin_amdgcn_global_load_lds(                         \
    (const __attribute__((address_space(1))) void*)(g),                       \
    (__attribute__((address_space(3))) void*)(l), 16, 0, 0)

#define MFMA16(a, b, c) __builtin_amdgcn_mfma_f32_16x16x32_f16((a), (b), (c), 0, 0, 0)
#define BAR() __builtin_amdgcn_s_barrier()
#define PRIO1() __builtin_amdgcn_s_setprio(1)
#define PRIO0() __builtin_amdgcn_s_setprio(0)
#define WAIT_LGKM(n) asm volatile("s_waitcnt lgkmcnt(" #n ")" ::: "memory")
#define WAIT_VM(n)   asm volatile("s_waitcnt vmcnt(" #n ")" ::: "memory")

// ---------------------------------------------------------------------------
// fp16 GEMM family, 256xBNT tile, 8 waves, r10 never-drain counted pipeline.
//   TERMS==3 (scores, BNT=256): 3-term split (Ah*Bh + Ah*Bl + Al*Bh), 6 phases.
//   TERMS==2 (proj,   BNT=256): 2-term (A*Bh + A*Bl), A single plane, 4 phases,
//     3 barriers/tile. FIFO: vm(4)@P0 (retires Bl(t)), vm(2)@P2 (retires
//     A,Bh(t+1)), lgkm(4)@P0, (4)@P1, (0)@P2 — no cold drain in-loop.
//   TERMS==1 (PV,     BNT=128): 1-term, K-tile 64 (k-half planes), 2 phases.
// LDS planes [rows][64B], 4-slot XOR swizzle (slot = chunk ^ ((row>>1)&3)),
// both sides, 0-conflict (verified r10). XCD-bijective block swizzle kept.
// ---------------------------------------------------------------------------
template <int TERMS, int CMODE, int BNT>
__global__ __launch_bounds__(512, 1) void bgemm256(
    const _Float16* __restrict__ Ah_, const _Float16* __restrict__ Al_, long sAz,
    const _Float16* __restrict__ Bh_, const _Float16* __restrict__ Bl_, long sBz,
    int lda, int ldb,
    void* __restrict__ C1, void* __restrict__ C2, int ldc, long sCz,
    const float* __restrict__ bias, int K)
{
    extern __shared__ char smem[];
    constexpr int NW_N  = BNT / 64;
    constexpr int NW_M  = 8 / NW_N;
    constexpr int WM    = 256 / NW_M;
    constexpr int MI    = WM / 16;
    constexpr int APLANE = 16384;            // 256 rows x 64 B
    constexpr int BPLANE = BNT * 64;
    constexpr int NAP    = (TERMS == 2) ? 1 : 2;   // A planes per buffer
    constexpr int BOFF   = NAP * APLANE;
    constexpr int BUFSZ  = NAP * APLANE + 2 * BPLANE;

    // ---- XCD-aware bijective block swizzle (T1, m204) ----
    int bx, by, bz;
    {
        const int gx = gridDim.x, gy = gridDim.y;
        const int nwg = gx * gy * gridDim.z;
        const int wg = blockIdx.x + gx * (blockIdx.y + gy * blockIdx.z);
        const int q = nwg >> 3, r = nwg & 7;
        const int xcd = wg & 7, i = wg >> 3;
        const int nid = (xcd < r) ? xcd * (q + 1) + i
                                  : r * (q + 1) + (xcd - r) * q + i;
        bx = nid % gx;
        const int tmp = nid / gx;
        by = tmp % gy;
        bz = tmp / gy;
    }

    const int t = threadIdx.x;
    const int z = bz;
    const int m0 = by * 256;
    const int n0 = bx * BNT;
    const int lane = t & 63, wid = t >> 6;
    const int wr = wid / NW_N, wc = wid % NW_N;
    const int fr = lane & 15, fq = lane >> 4;
    const int lrow = lane >> 2, lslot = lane & 3;

    const _Float16* Ahz = Ah_ + (long)z * sAz;
    const _Float16* Alz = (TERMS == 3) ? Al_ + (long)z * sAz : nullptr;
    const _Float16* Bhz = Bh_ + (long)z * sBz;
    const _Float16* Blz = (TERMS >= 2) ? Bl_ + (long)z * sBz : nullptr;

    // stage plane p (T3: p=A-hi/lo; T2: p=0 only; T1: k-half p)
    auto stA = [&](int tile, int p) {
        const _Float16* plane = (TERMS == 3 && p) ? Alz : Ahz;
        char* lbase = smem + (tile & 1) * BUFSZ + p * APLANE;
#pragma unroll
        for (int i = 0; i < 2; ++i) {
            const int row = wid * 32 + i * 16 + lrow;
            const int chunk = lslot ^ ((row >> 1) & 3);
            const long kk = (TERMS == 1) ? (long)tile * 64 + p * 32 + chunk * 8
                                         : (long)tile * 32 + chunk * 8;
            GLD16(plane + (long)(m0 + row) * lda + kk,
                  lbase + (wid * 32 + i * 16) * 64);
        }
    };
    auto stB = [&](int tile, int p) {
        const _Float16* plane = (TERMS >= 2 && p) ? Blz : Bhz;
        char* lbase = smem + (tile & 1) * BUFSZ + BOFF + p * BPLANE;
        if (TERMS >= 2) {
#pragma unroll
            for (int i = 0; i < 2; ++i) {
                const int row = wid * 32 + i * 16 + lrow;
                const int chunk = lslot ^ ((row >> 1) & 3);
                const long kk = (long)tile * 32 + chunk * 8;
                GLD16(plane + (long)(n0 + row) * ldb + kk,
                      lbase + (wid * 32 + i * 16) * 64);
            }
        } else {
            const int row = wid * 16 + lrow;
            const int chunk = lslot ^ ((row >> 1) & 3);
            const long kk = (long)tile * 64 + p * 32 + chunk * 8;
            GLD16(plane + (long)(n0 + row) * ldb + kk, lbase + (wid * 16) * 64);
        }
    };
    auto rdA = [&](int buf, int p, int mi) -> f16x8 {
        const int row = wr * WM + mi * 16 + fr;
        const int slot = fq ^ ((row >> 1) & 3);
        return *(const f16x8*)(smem + buf * BUFSZ + p * APLANE +
                               row * 64 + slot * 16);
    };
    auto rdB = [&](int buf, int p, int ni) -> f16x8 {
        const int row = wc * 64 + ni * 16 + fr;
        const int slot = fq ^ ((row >> 1) & 3);
        return *(const f16x8*)(smem + buf * BUFSZ + BOFF + p * BPLANE +
                               row * 64 + slot * 16);
    };

    f32x4 acc[MI][4] = {};
    const int ktiles = K / ((TERMS == 1) ? 64 : 32);

    if constexpr (TERMS == 3) {
        f16x8 b0[4], b1[4], aA[4], aB[4], aA2[4], aB2[4];
        auto mb = [&](int base, f16x8 (&A)[4], f16x8 (&B)[4]) {
#pragma unroll
            for (int mi = 0; mi < 4; ++mi)
#pragma unroll
                for (int ni = 0; ni < 4; ++ni)
                    acc[base + mi][ni] = MFMA16(A[mi], B[ni], acc[base + mi][ni]);
        };
        stA(0, 0); stB(0, 0); stA(0, 1); stB(0, 1);
        WAIT_VM(0);
        BAR();
#pragma unroll
        for (int ni = 0; ni < 4; ++ni) b0[ni] = rdB(0, 0, ni);
#pragma unroll
        for (int mi = 0; mi < 4; ++mi) aA[mi] = rdA(0, 0, mi);
#pragma unroll
        for (int mi = 0; mi < 4; ++mi) aB[mi] = rdA(0, 0, 4 + mi);

        for (int tt = 0; tt < ktiles; ++tt) {
            const int buf = tt & 1;
            const bool pf = (tt + 1 < ktiles);
            // P0
            if (pf) stA(tt + 1, 0);
            BAR();
            WAIT_LGKM(4);
            PRIO1(); mb(0, aA, b0); PRIO0();
            BAR();
            // P1
            if (pf) { WAIT_VM(2); stB(tt + 1, 0); }
            else    { WAIT_VM(0); }
            BAR();
#pragma unroll
            for (int ni = 0; ni < 4; ++ni) b1[ni] = rdB(buf, 1, ni);
            WAIT_LGKM(4);
            PRIO1(); mb(4, aB, b0); PRIO0();
            BAR();
            // P2
#pragma unroll
            for (int mi = 0; mi < 4; ++mi) aA2[mi] = rdA(buf, 1, mi);
            if (pf) stA(tt + 1, 1);
            BAR();
            WAIT_LGKM(4);
            PRIO1(); mb(0, aA, b1); PRIO0();
            BAR();
            // P3
#pragma unroll
            for (int mi = 0; mi < 4; ++mi) aB2[mi] = rdA(buf, 1, 4 + mi);
            if (pf) stB(tt + 1, 1);
            BAR();
            PRIO1(); mb(4, aB, b1); PRIO0();
            BAR();
            // P4
            WAIT_LGKM(4);
            PRIO1(); mb(0, aA2, b0); PRIO0();
            BAR();
            // P5
            if (pf) WAIT_VM(4);
            WAIT_LGKM(0);
            BAR();
            PRIO1(); mb(4, aB2, b0); PRIO0();
            if (pf) {
                const int nb = buf ^ 1;
#pragma unroll
                for (int ni = 0; ni < 4; ++ni) b0[ni] = rdB(nb, 0, ni);
#pragma unroll
                for (int mi = 0; mi < 4; ++mi) aA[mi] = rdA(nb, 0, mi);
#pragma unroll
                for (int mi = 0; mi < 4; ++mi) aB[mi] = rdA(nb, 0, 4 + mi);
            }
        }
    } else if constexpr (TERMS == 2) {
        f16x8 b0h[4], b0l[4], aA[4], aB[4];
        auto mb = [&](int base, f16x8 (&A)[4], f16x8 (&B)[4]) {
#pragma unroll
            for (int mi = 0; mi < 4; ++mi)
#pragma unroll
                for (int ni = 0; ni < 4; ++ni)
                    acc[base + mi][ni] = MFMA16(A[mi], B[ni], acc[base + mi][ni]);
        };
        stA(0, 0); stB(0, 0); stB(0, 1);
        WAIT_VM(0);
        BAR();
#pragma unroll
        for (int ni = 0; ni < 4; ++ni) b0h[ni] = rdB(0, 0, ni);
#pragma unroll
        for (int mi = 0; mi < 4; ++mi) aA[mi] = rdA(0, 0, mi);
#pragma unroll
        for (int mi = 0; mi < 4; ++mi) aB[mi] = rdA(0, 0, 4 + mi);

        for (int tt = 0; tt < ktiles; ++tt) {
            const int buf = tt & 1;
            const bool pf = (tt + 1 < ktiles);
            // P0: stage A,Bh(t+1); vm(4) retires Bl(t); BAR seals B-lo plane
            if (pf) { stA(tt + 1, 0); stB(tt + 1, 0); WAIT_VM(4); }
            else    { WAIT_VM(0); }
            BAR();
            WAIT_LGKM(4);                         // b0h,aA landed (aB left)
            PRIO1(); mb(0, aA, b0h); PRIO0();
            // P1: stage Bl(t+1); pre-read b0l
            if (pf) stB(tt + 1, 1);
#pragma unroll
            for (int ni = 0; ni < 4; ++ni) b0l[ni] = rdB(buf, 1, ni);
            WAIT_LGKM(4);                         // aB landed (b0l left)
            PRIO1(); mb(4, aB, b0h); PRIO0();
            // P2: vm(2) retires A,Bh(t+1); BAR seals them for tail reads
            if (pf) WAIT_VM(2);
            BAR();
            WAIT_LGKM(0);                         // b0l landed
            PRIO1(); mb(0, aA, b0l); PRIO0();
            // P3
            PRIO1(); mb(4, aB, b0l); PRIO0();
            if (pf) {
                const int nb = buf ^ 1;
#pragma unroll
                for (int ni = 0; ni < 4; ++ni) b0h[ni] = rdB(nb, 0, ni);
#pragma unroll
                for (int mi = 0; mi < 4; ++mi) aA[mi] = rdA(nb, 0, mi);
#pragma unroll
                for (int mi = 0; mi < 4; ++mi) aB[mi] = rdA(nb, 0, 4 + mi);
            }
            BAR();
        }
    } else {  // TERMS == 1 (PV, BNT=128, MI=4)
        f16x8 b0[4], b1[4], a0[4], a1[4];
        auto mb = [&](f16x8 (&A)[4], f16x8 (&B)[4]) {
#pragma unroll
            for (int mi = 0; mi < 4; ++mi)
#pragma unroll
                for (int ni = 0; ni < 4; ++ni)
                    acc[mi][ni] = MFMA16(A[mi], B[ni], acc[mi][ni]);
        };
        stA(0, 0); stB(0, 0); stA(0, 1); stB(0, 1);
        WAIT_VM(0);
        BAR();
#pragma unroll
        for (int ni = 0; ni < 4; ++ni) b0[ni] = rdB(0, 0, ni);
#pragma unroll
        for (int mi = 0; mi < 4; ++mi) a0[mi] = rdA(0, 0, mi);

        for (int tt = 0; tt < ktiles; ++tt) {
            const int buf = tt & 1;
            const bool pf = (tt + 1 < ktiles);
            // P0
            if (pf) { stA(tt + 1, 0); stB(tt + 1, 0); WAIT_VM(3); }
            else    { WAIT_VM(0); }
            BAR();
#pragma unroll
            for (int ni = 0; ni < 4; ++ni) b1[ni] = rdB(buf, 1, ni);
#pragma unroll
            for (int mi = 0; mi < 4; ++mi) a1[mi] = rdA(buf, 1, mi);
            WAIT_LGKM(8);
            PRIO1(); mb(a0, b0); PRIO0();
            BAR();
            // P1
            if (pf) { stA(tt + 1, 1); stB(tt + 1, 1); WAIT_VM(3); }
            WAIT_LGKM(0);
            BAR();
            PRIO1(); mb(a1, b1); PRIO0();
            if (pf) {
                const int nb = buf ^ 1;
#pragma unroll
                for (int ni = 0; ni < 4; ++ni) b0[ni] = rdB(nb, 0, ni);
#pragma unroll
                for (int mi = 0; mi < 4; ++mi) a0[mi] = rdA(nb, 0, mi);
            }
        }
    }

    // ---------------- epilogue ----------------
#pragma unroll
    for (int mi = 0; mi < MI; ++mi) {
        const int rbase = m0 + wr * WM + mi * 16 + fq * 4;
#pragma unroll
        for (int ni = 0; ni < 4; ++ni) {
            const int col = n0 + wc * 64 + ni * 16 + fr;
            f32x4 a = acc[mi][ni];
            if (CMODE != CM_F32) {
                const float bv = bias[col];
#pragma unroll
                for (int j = 0; j < 4; ++j) a[j] += bv;
            }
            if (CMODE == CM_F32) {
                float* C = (float*)C1 + (long)z * sCz;
#pragma unroll
                for (int j = 0; j < 4; ++j)
                    C[(long)(rbase + j) * ldc + col] = a[j];
            } else if (CMODE == CM_SPLIT) {
                _Float16* Ch = (_Float16*)C1;
                _Float16* Cl = (_Float16*)C2;
#pragma unroll
                for (int j = 0; j < 4; ++j) {
                    const float q = a[j];
                    const _Float16 h = (_Float16)q;
                    Ch[(long)(rbase + j) * ldc + col] = h;
                    Cl[(long)(rbase + j) * ldc + col] = (_Float16)(q - (float)h);
                }
            } else {  // CM_TRANSV: Vt[b][col][s] f16
                const int b_ = rbase >> 11;
                const int s_ = rbase & (S - 1);
                f16x4 h;
#pragma unroll
                for (int j = 0; j < 4; ++j) h[j] = (_Float16)a[j];
                *(f16x4*)((_Float16*)C1 + ((long)b_ * D + col) * S + s_) = h;
            }
        }
    }
}

// ---------------------------------------------------------------------------
// X -> single fp16 plane (2-term proj drops the Xl cross term; err ~5e-4).
__global__ __launch_bounds__(256) void xsplit(
    const float* __restrict__ X, _Float16* __restrict__ Xh)
{
    const long i = ((long)blockIdx.x * 256 + threadIdx.x) * 8;
    f32x4 v0 = *(const f32x4*)(X + i);
    f32x4 v1 = *(const f32x4*)(X + i + 4);
    f16x8 h;
#pragma unroll
    for (int j = 0; j < 4; ++j) { h[j] = (_Float16)v0[j]; h[4 + j] = (_Float16)v1[j]; }
    *(f16x8*)(Xh + i) = h;
}

// ---------------------------------------------------------------------------
__global__ void wsplit(const float* __restrict__ W0, const float* __restrict__ W1,
                       const float* __restrict__ W2,
                       _Float16* __restrict__ Th, _Float16* __restrict__ Tl)
{
    const float* W = blockIdx.z == 0 ? W0 : (blockIdx.z == 1 ? W1 : W2);
    _Float16* th = Th + (long)blockIdx.z * 1024 * 1024;
    _Float16* tl = Tl + (long)blockIdx.z * 1024 * 1024;
    __shared__ float tile[32][33];
    const int bx = blockIdx.x * 32, by = blockIdx.y * 32;
    const int tx = threadIdx.x, ty = threadIdx.y;
#pragma unroll
    for (int i = ty; i < 32; i += 8) tile[i][tx] = W[(long)(by + i) * 1024 + bx + tx];
    __syncthreads();
#pragma unroll
    for (int i = ty; i < 32; i += 8) {
        const float v = tile[tx][i];
        const _Float16 h = (_Float16)v;
        th[(long)(bx + i) * 1024 + by + tx] = h;
        tl[(long)(bx + i) * 1024 + by + tx] = (_Float16)(v - (float)h);
    }
}

// ---------------------------------------------------------------------------
// Fused row softmax: f32 score row -> P = exp(s-m)/l as fp16, in-place.
__global__ __launch_bounds__(256) void pconv(float* __restrict__ Sb)
{
    const long row = blockIdx.x;
    float* p = Sb + row * (long)S;
    const int t = threadIdx.x;

    f32x4 x0 = *(const f32x4*)(p + t * 8);
    f32x4 x1 = *(const f32x4*)(p + t * 8 + 4);

    float m = -3.4e38f;
#pragma unroll
    for (int j = 0; j < 4; ++j) m = fmaxf(m, fmaxf(x0[j], x1[j]));
#pragma unroll
    for (int o = 32; o >= 1; o >>= 1) m = fmaxf(m, __shfl_xor(m, o));

    __shared__ float wm[4], wsum[4];
    const int wid = t >> 6, lane = t & 63;
    if (lane == 0) wm[wid] = m;
    __syncthreads();
    m = fmaxf(fmaxf(wm[0], wm[1]), fmaxf(wm[2], wm[3]));

    float e[8], ssum = 0.f;
#pragma unroll
    for (int j = 0; j < 4; ++j) {
        e[j]     = exp2f((x0[j] - m) * LOG2E);
        e[4 + j] = exp2f((x1[j] - m) * LOG2E);
        ssum += e[j] + e[4 + j];
    }
#pragma unroll
    for (int o = 32; o >= 1; o >>= 1) ssum += __shfl_xor(ssum, o);
    if (lane == 0) wsum[wid] = ssum;
    __syncthreads();
    const float invl = 1.0f / (wsum[0] + wsum[1] + wsum[2] + wsum[3]);

    f16x8 outv;
#pragma unroll
    for (int j = 0; j < 8; ++j) outv[j] = (_Float16)(e[j] * invl);
    *(f16x8*)((_Float16*)p + t * 8) = outv;
}

// ---------------------------------------------------------------------------
extern "C" void kernel_launch(void* const* d_in, const int* in_sizes, int n_in,
                              void* d_out, int out_size, void* d_ws, size_t ws_size,
                              hipStream_t stream)
{
    const float* X  = (const float*)d_in[0];
    const float* Wq = (const float*)d_in[1];
    const float* bq = (const float*)d_in[2];
    const float* Wk = (const float*)d_in[3];
    const float* bk = (const float*)d_in[4];
    const float* Wv = (const float*)d_in[5];
    const float* bv = (const float*)d_in[6];
    float* out = (float*)d_out;
    char* ws = (char*)d_ws;
    const size_t MB = 1u << 20;

    // layout (236 MB):
    // [0,6) Wh[3]  [6,12) Wl[3]  [12,44) Qh  [44,76) Ql  [76,108) Kh
    // [108,140) Kl  [140,172) Vt  [172,236) Sb f32 [4][S][S] (P f16 in-place)
    // Xh (32 MB, f16) aliases Sb's first half [172,204) — dead before scores.
    _Float16* Wh = (_Float16*)ws;          _Float16* Wl = (_Float16*)(ws + 6 * MB);
    _Float16* Qh = (_Float16*)(ws + 12 * MB);  _Float16* Ql = (_Float16*)(ws + 44 * MB);
    _Float16* Kh = (_Float16*)(ws + 76 * MB);  _Float16* Kl = (_Float16*)(ws + 108 * MB);
    _Float16* Vt = (_Float16*)(ws + 140 * MB);
    float*    Sb = (float*)(ws + 172 * MB);
    _Float16* Xh = (_Float16*)(ws + 172 * MB);

    const int LDS_T3 = 131072;   // 2 bufs x (2A + 2B) x 16K
    const int LDS_T2 = 98304;    // 2 bufs x (1A + 2B) x 16K
    const int LDS_T1 = 98304;    // 2 bufs x (2A x 16K + 2B x 8K)
    hipFuncSetAttribute(reinterpret_cast<const void*>(&bgemm256<2, CM_SPLIT, 256>),
                        hipFuncAttributeMaxDynamicSharedMemorySize, LDS_T2);
    hipFuncSetAttribute(reinterpret_cast<const void*>(&bgemm256<2, CM_TRANSV, 256>),
                        hipFuncAttributeMaxDynamicSharedMemorySize, LDS_T2);
    hipFuncSetAttribute(reinterpret_cast<const void*>(&bgemm256<3, CM_F32, 256>),
                        hipFuncAttributeMaxDynamicSharedMemorySize, LDS_T3);
    hipFuncSetAttribute(reinterpret_cast<const void*>(&bgemm256<1, CM_F32, 128>),
                        hipFuncAttributeMaxDynamicSharedMemorySize, LDS_T1);

    // 1) convert X -> f16 single plane; W -> f16 hi/lo split (transposed)
    xsplit<<<dim3(8192), 256, 0, stream>>>(X, Xh);
    wsplit<<<dim3(32, 32, 3), dim3(32, 8), 0, stream>>>(Wq, Wk, Wv, Wh, Wl);

    // 2) projections: 2-term fp16 (Xh * (Wh + Wl))
    const long MW = 1024 * 1024;
    bgemm256<2, CM_SPLIT, 256><<<dim3(D / 256, 64, 1), 512, LDS_T2, stream>>>(
        Xh, nullptr, 0, Wh, Wl, 0, D, D, Qh, Ql, D, 0, bq, D);
    bgemm256<2, CM_SPLIT, 256><<<dim3(D / 256, 64, 1), 512, LDS_T2, stream>>>(
        Xh, nullptr, 0, Wh + MW, Wl + MW, 0, D, D, Kh, Kl, D, 0, bk, D);
    bgemm256<2, CM_TRANSV, 256><<<dim3(D / 256, 64, 1), 512, LDS_T2, stream>>>(
        Xh, nullptr, 0, Wh + 2 * MW, Wl + 2 * MW, 0, D, D, Vt, nullptr, 0, 0, bv, D);

    // 3) per 4-batch group: scores (3-term) -> in-place softmax->f16 P -> PV
    for (int g = 0; g < 2; ++g) {
        const int b0 = g * 4;
        bgemm256<3, CM_F32, 256><<<dim3(S / 256, S / 256, 4), 512, LDS_T3, stream>>>(
            Qh + (long)b0 * S * D, Ql + (long)b0 * S * D, (long)S * D,
            Kh + (long)b0 * S * D, Kl + (long)b0 * S * D, (long)S * D,
            D, D, Sb, nullptr, S, (long)S * S, nullptr, D);
        pconv<<<dim3(4 * S), 256, 0, stream>>>(Sb);
        // PV: A = f16 P rows embedded in f32 buffer (lda = 2S f16 elements)
        bgemm256<1, CM_F32, 128><<<dim3(D / 128, S / 256, 4), 512, LDS_T1, stream>>>(
            (const _Float16*)Sb, nullptr, 2L * S * S,
            Vt + (long)b0 * D * S, nullptr, (long)D * S,
            2 * S, S, out + (long)b0 * S * D, nullptr, D, (long)S * D, nullptr, S);
    }
}

// Round 14
// 455.923 us; speedup vs baseline: 1.8266x; 1.1299x over previous
//
#include <hip/hip_runtime.h>
#include <hip/hip_bf16.h>

// B=8, S=2048, D=1024, fp32 in/out.
static constexpr int S = 2048;
static constexpr int D = 1024;
static constexpr int NB = 8;

#define LOG2E 1.4426950408889634f

typedef float    f32x4  __attribute__((ext_vector_type(4)));
typedef _Float16 f16x4  __attribute__((ext_vector_type(4)));
typedef _Float16 f16x8  __attribute__((ext_vector_type(8)));

#define CM_F32    0
#define CM_SPLIT  1
#define CM_TRANSV 2
#define CM_F16    3

#define GLD16(g, l) __builtin_amdgcn_global_load_lds(                         \
    (const __attribute__((address_space(1))) void*)(g),                       \
    (__attribute__((address_space(3))) void*)(l), 16, 0, 0)

#define MFMA16(a, b, c) __builtin_amdgcn_mfma_f32_16x16x32_f16((a), (b), (c), 0, 0, 0)
#define BAR() __builtin_amdgcn_s_barrier()
#define PRIO1() __builtin_amdgcn_s_setprio(1)
#define PRIO0() __builtin_amdgcn_s_setprio(0)
#define WAIT_LGKM(n) asm volatile("s_waitcnt lgkmcnt(" #n ")" ::: "memory")
#define WAIT_VM(n)   asm volatile("s_waitcnt vmcnt(" #n ")" ::: "memory")

// ---------------------------------------------------------------------------
// fp16 GEMM family, 256xBNT tile, 8 waves, never-drain counted pipeline (r10).
//   TERMS==2 (proj + scores, BNT=256): 2-term (A*Bh + A*Bl), A single plane,
//     4 phases, 3 barriers/tile. FIFO: vm(4)@P0 (retires Bl(t)), vm(2)@P2
//     (retires A,Bh(t+1)), lgkm(4)@P0, (4)@P1, (0)@P2 — no in-loop drain.
//   TERMS==1 (PV, BNT=128): 1-term, K-tile 64 (k-half planes), 2 phases.
// LDS planes [rows][64B], 4-slot XOR swizzle (slot = chunk ^ ((row>>1)&3)),
// both sides, 0-conflict (verified r10). XCD-bijective block swizzle kept.
// Epilogues: CM_F32 (f32 store) | CM_SPLIT (f16 h+l) | CM_TRANSV (f16,
// transposed Vt[b][d][s]) | CM_F16 (single f16).
// ---------------------------------------------------------------------------
template <int TERMS, int CMODE, int BNT>
__global__ __launch_bounds__(512, 1) void bgemm256(
    const _Float16* __restrict__ Ah_, const _Float16* __restrict__ Al_, long sAz,
    const _Float16* __restrict__ Bh_, const _Float16* __restrict__ Bl_, long sBz,
    int lda, int ldb,
    void* __restrict__ C1, void* __restrict__ C2, int ldc, long sCz,
    const float* __restrict__ bias, int K)
{
    extern __shared__ char smem[];
    constexpr int NW_N  = BNT / 64;
    constexpr int NW_M  = 8 / NW_N;
    constexpr int WM    = 256 / NW_M;
    constexpr int MI    = WM / 16;
    constexpr int APLANE = 16384;            // 256 rows x 64 B
    constexpr int BPLANE = BNT * 64;
    constexpr int NAP    = (TERMS == 2) ? 1 : 2;   // A planes per buffer
    constexpr int BOFF   = NAP * APLANE;
    constexpr int BUFSZ  = NAP * APLANE + 2 * BPLANE;

    // ---- XCD-aware bijective block swizzle (T1, m204) ----
    int bx, by, bz;
    {
        const int gx = gridDim.x, gy = gridDim.y;
        const int nwg = gx * gy * gridDim.z;
        const int wg = blockIdx.x + gx * (blockIdx.y + gy * blockIdx.z);
        const int q = nwg >> 3, r = nwg & 7;
        const int xcd = wg & 7, i = wg >> 3;
        const int nid = (xcd < r) ? xcd * (q + 1) + i
                                  : r * (q + 1) + (xcd - r) * q + i;
        bx = nid % gx;
        const int tmp = nid / gx;
        by = tmp % gy;
        bz = tmp / gy;
    }

    const int t = threadIdx.x;
    const int z = bz;
    const int m0 = by * 256;
    const int n0 = bx * BNT;
    const int lane = t & 63, wid = t >> 6;
    const int wr = wid / NW_N, wc = wid % NW_N;
    const int fr = lane & 15, fq = lane >> 4;
    const int lrow = lane >> 2, lslot = lane & 3;

    const _Float16* Ahz = Ah_ + (long)z * sAz;
    const _Float16* Bhz = Bh_ + (long)z * sBz;
    const _Float16* Blz = (TERMS == 2) ? Bl_ + (long)z * sBz : nullptr;

    // stage plane p (T2: p=0 only; T1: k-half p)
    auto stA = [&](int tile, int p) {
        const _Float16* plane = Ahz;
        char* lbase = smem + (tile & 1) * BUFSZ + p * APLANE;
#pragma unroll
        for (int i = 0; i < 2; ++i) {
            const int row = wid * 32 + i * 16 + lrow;
            const int chunk = lslot ^ ((row >> 1) & 3);
            const long kk = (TERMS == 1) ? (long)tile * 64 + p * 32 + chunk * 8
                                         : (long)tile * 32 + chunk * 8;
            GLD16(plane + (long)(m0 + row) * lda + kk,
                  lbase + (wid * 32 + i * 16) * 64);
        }
    };
    auto stB = [&](int tile, int p) {
        const _Float16* plane = (TERMS == 2 && p) ? Blz : Bhz;
        char* lbase = smem + (tile & 1) * BUFSZ + BOFF + p * BPLANE;
        if (TERMS == 2) {
#pragma unroll
            for (int i = 0; i < 2; ++i) {
                const int row = wid * 32 + i * 16 + lrow;
                const int chunk = lslot ^ ((row >> 1) & 3);
                const long kk = (long)tile * 32 + chunk * 8;
                GLD16(plane + (long)(n0 + row) * ldb + kk,
                      lbase + (wid * 32 + i * 16) * 64);
            }
        } else {
            const int row = wid * 16 + lrow;
            const int chunk = lslot ^ ((row >> 1) & 3);
            const long kk = (long)tile * 64 + p * 32 + chunk * 8;
            GLD16(plane + (long)(n0 + row) * ldb + kk, lbase + (wid * 16) * 64);
        }
    };
    auto rdA = [&](int buf, int p, int mi) -> f16x8 {
        const int row = wr * WM + mi * 16 + fr;
        const int slot = fq ^ ((row >> 1) & 3);
        return *(const f16x8*)(smem + buf * BUFSZ + p * APLANE +
                               row * 64 + slot * 16);
    };
    auto rdB = [&](int buf, int p, int ni) -> f16x8 {
        const int row = wc * 64 + ni * 16 + fr;
        const int slot = fq ^ ((row >> 1) & 3);
        return *(const f16x8*)(smem + buf * BUFSZ + BOFF + p * BPLANE +
                               row * 64 + slot * 16);
    };

    f32x4 acc[MI][4] = {};
    const int ktiles = K / ((TERMS == 1) ? 64 : 32);

    if constexpr (TERMS == 2) {
        f16x8 b0h[4], b0l[4], aA[4], aB[4];
        auto mb = [&](int base, f16x8 (&A)[4], f16x8 (&B)[4]) {
#pragma unroll
            for (int mi = 0; mi < 4; ++mi)
#pragma unroll
                for (int ni = 0; ni < 4; ++ni)
                    acc[base + mi][ni] = MFMA16(A[mi], B[ni], acc[base + mi][ni]);
        };
        stA(0, 0); stB(0, 0); stB(0, 1);
        WAIT_VM(0);
        BAR();
#pragma unroll
        for (int ni = 0; ni < 4; ++ni) b0h[ni] = rdB(0, 0, ni);
#pragma unroll
        for (int mi = 0; mi < 4; ++mi) aA[mi] = rdA(0, 0, mi);
#pragma unroll
        for (int mi = 0; mi < 4; ++mi) aB[mi] = rdA(0, 0, 4 + mi);

        for (int tt = 0; tt < ktiles; ++tt) {
            const int buf = tt & 1;
            const bool pf = (tt + 1 < ktiles);
            // P0: stage A,Bh(t+1); vm(4) retires Bl(t); BAR seals B-lo plane
            if (pf) { stA(tt + 1, 0); stB(tt + 1, 0); WAIT_VM(4); }
            else    { WAIT_VM(0); }
            BAR();
            WAIT_LGKM(4);                         // b0h,aA landed (aB left)
            PRIO1(); mb(0, aA, b0h); PRIO0();
            // P1: stage Bl(t+1); pre-read b0l
            if (pf) stB(tt + 1, 1);
#pragma unroll
            for (int ni = 0; ni < 4; ++ni) b0l[ni] = rdB(buf, 1, ni);
            WAIT_LGKM(4);                         // aB landed (b0l left)
            PRIO1(); mb(4, aB, b0h); PRIO0();
            // P2: vm(2) retires A,Bh(t+1); BAR seals them for tail reads
            if (pf) WAIT_VM(2);
            BAR();
            WAIT_LGKM(0);                         // b0l landed
            PRIO1(); mb(0, aA, b0l); PRIO0();
            // P3
            PRIO1(); mb(4, aB, b0l); PRIO0();
            if (pf) {
                const int nb = buf ^ 1;
#pragma unroll
                for (int ni = 0; ni < 4; ++ni) b0h[ni] = rdB(nb, 0, ni);
#pragma unroll
                for (int mi = 0; mi < 4; ++mi) aA[mi] = rdA(nb, 0, mi);
#pragma unroll
                for (int mi = 0; mi < 4; ++mi) aB[mi] = rdA(nb, 0, 4 + mi);
            }
            BAR();
        }
    } else {  // TERMS == 1 (PV, BNT=128, MI=4)
        f16x8 b0[4], b1[4], a0[4], a1[4];
        auto mb = [&](f16x8 (&A)[4], f16x8 (&B)[4]) {
#pragma unroll
            for (int mi = 0; mi < 4; ++mi)
#pragma unroll
                for (int ni = 0; ni < 4; ++ni)
                    acc[mi][ni] = MFMA16(A[mi], B[ni], acc[mi][ni]);
        };
        stA(0, 0); stB(0, 0); stA(0, 1); stB(0, 1);
        WAIT_VM(0);
        BAR();
#pragma unroll
        for (int ni = 0; ni < 4; ++ni) b0[ni] = rdB(0, 0, ni);
#pragma unroll
        for (int mi = 0; mi < 4; ++mi) a0[mi] = rdA(0, 0, mi);

        for (int tt = 0; tt < ktiles; ++tt) {
            const int buf = tt & 1;
            const bool pf = (tt + 1 < ktiles);
            // P0
            if (pf) { stA(tt + 1, 0); stB(tt + 1, 0); WAIT_VM(3); }
            else    { WAIT_VM(0); }
            BAR();
#pragma unroll
            for (int ni = 0; ni < 4; ++ni) b1[ni] = rdB(buf, 1, ni);
#pragma unroll
            for (int mi = 0; mi < 4; ++mi) a1[mi] = rdA(buf, 1, mi);
            WAIT_LGKM(8);
            PRIO1(); mb(a0, b0); PRIO0();
            BAR();
            // P1
            if (pf) { stA(tt + 1, 1); stB(tt + 1, 1); WAIT_VM(3); }
            WAIT_LGKM(0);
            BAR();
            PRIO1(); mb(a1, b1); PRIO0();
            if (pf) {
                const int nb = buf ^ 1;
#pragma unroll
                for (int ni = 0; ni < 4; ++ni) b0[ni] = rdB(nb, 0, ni);
#pragma unroll
                for (int mi = 0; mi < 4; ++mi) a0[mi] = rdA(nb, 0, mi);
            }
        }
    }

    // ---------------- epilogue ----------------
#pragma unroll
    for (int mi = 0; mi < MI; ++mi) {
        const int rbase = m0 + wr * WM + mi * 16 + fq * 4;
#pragma unroll
        for (int ni = 0; ni < 4; ++ni) {
            const int col = n0 + wc * 64 + ni * 16 + fr;
            f32x4 a = acc[mi][ni];
            if (CMODE != CM_F32) {
                const float bv = bias[col];
#pragma unroll
                for (int j = 0; j < 4; ++j) a[j] += bv;
            }
            if (CMODE == CM_F32) {
                float* C = (float*)C1 + (long)z * sCz;
#pragma unroll
                for (int j = 0; j < 4; ++j)
                    C[(long)(rbase + j) * ldc + col] = a[j];
            } else if (CMODE == CM_F16) {
                _Float16* Ch = (_Float16*)C1;
#pragma unroll
                for (int j = 0; j < 4; ++j)
                    Ch[(long)(rbase + j) * ldc + col] = (_Float16)a[j];
            } else if (CMODE == CM_SPLIT) {
                _Float16* Ch = (_Float16*)C1;
                _Float16* Cl = (_Float16*)C2;
#pragma unroll
                for (int j = 0; j < 4; ++j) {
                    const float q = a[j];
                    const _Float16 h = (_Float16)q;
                    Ch[(long)(rbase + j) * ldc + col] = h;
                    Cl[(long)(rbase + j) * ldc + col] = (_Float16)(q - (float)h);
                }
            } else {  // CM_TRANSV: Vt[b][col][s] f16
                const int b_ = rbase >> 11;
                const int s_ = rbase & (S - 1);
                f16x4 h;
#pragma unroll
                for (int j = 0; j < 4; ++j) h[j] = (_Float16)a[j];
                *(f16x4*)((_Float16*)C1 + ((long)b_ * D + col) * S + s_) = h;
            }
        }
    }
}

// ---------------------------------------------------------------------------
// X -> single fp16 plane.
__global__ __launch_bounds__(256) void xsplit(
    const float* __restrict__ X, _Float16* __restrict__ Xh)
{
    const long i = ((long)blockIdx.x * 256 + threadIdx.x) * 8;
    f32x4 v0 = *(const f32x4*)(X + i);
    f32x4 v1 = *(const f32x4*)(X + i + 4);
    f16x8 h;
#pragma unroll
    for (int j = 0; j < 4; ++j) { h[j] = (_Float16)v0[j]; h[4 + j] = (_Float16)v1[j]; }
    *(f16x8*)(Xh + i) = h;
}

// ---------------------------------------------------------------------------
__global__ void wsplit(const float* __restrict__ W0, const float* __restrict__ W1,
                       const float* __restrict__ W2,
                       _Float16* __restrict__ Th, _Float16* __restrict__ Tl)
{
    const float* W = blockIdx.z == 0 ? W0 : (blockIdx.z == 1 ? W1 : W2);
    _Float16* th = Th + (long)blockIdx.z * 1024 * 1024;
    _Float16* tl = Tl + (long)blockIdx.z * 1024 * 1024;
    __shared__ float tile[32][33];
    const int bx = blockIdx.x * 32, by = blockIdx.y * 32;
    const int tx = threadIdx.x, ty = threadIdx.y;
#pragma unroll
    for (int i = ty; i < 32; i += 8) tile[i][tx] = W[(long)(by + i) * 1024 + bx + tx];
    __syncthreads();
#pragma unroll
    for (int i = ty; i < 32; i += 8) {
        const float v = tile[tx][i];
        const _Float16 h = (_Float16)v;
        th[(long)(bx + i) * 1024 + by + tx] = h;
        tl[(long)(bx + i) * 1024 + by + tx] = (_Float16)(v - (float)h);
    }
}

// ---------------------------------------------------------------------------
// Fused row softmax: f32 score row -> P = exp(s-m)/l as fp16, in-place.
__global__ __launch_bounds__(256) void pconv(float* __restrict__ Sb)
{
    const long row = blockIdx.x;
    float* p = Sb + row * (long)S;
    const int t = threadIdx.x;

    f32x4 x0 = *(const f32x4*)(p + t * 8);
    f32x4 x1 = *(const f32x4*)(p + t * 8 + 4);

    float m = -3.4e38f;
#pragma unroll
    for (int j = 0; j < 4; ++j) m = fmaxf(m, fmaxf(x0[j], x1[j]));
#pragma unroll
    for (int o = 32; o >= 1; o >>= 1) m = fmaxf(m, __shfl_xor(m, o));

    __shared__ float wm[4], wsum[4];
    const int wid = t >> 6, lane = t & 63;
    if (lane == 0) wm[wid] = m;
    __syncthreads();
    m = fmaxf(fmaxf(wm[0], wm[1]), fmaxf(wm[2], wm[3]));

    float e[8], ssum = 0.f;
#pragma unroll
    for (int j = 0; j < 4; ++j) {
        e[j]     = exp2f((x0[j] - m) * LOG2E);
        e[4 + j] = exp2f((x1[j] - m) * LOG2E);
        ssum += e[j] + e[4 + j];
    }
#pragma unroll
    for (int o = 32; o >= 1; o >>= 1) ssum += __shfl_xor(ssum, o);
    if (lane == 0) wsum[wid] = ssum;
    __syncthreads();
    const float invl = 1.0f / (wsum[0] + wsum[1] + wsum[2] + wsum[3]);

    f16x8 outv;
#pragma unroll
    for (int j = 0; j < 8; ++j) outv[j] = (_Float16)(e[j] * invl);
    *(f16x8*)((_Float16*)p + t * 8) = outv;
}

// ---------------------------------------------------------------------------
extern "C" void kernel_launch(void* const* d_in, const int* in_sizes, int n_in,
                              void* d_out, int out_size, void* d_ws, size_t ws_size,
                              hipStream_t stream)
{
    const float* X  = (const float*)d_in[0];
    const float* Wq = (const float*)d_in[1];
    const float* bq = (const float*)d_in[2];
    const float* Wk = (const float*)d_in[3];
    const float* bk = (const float*)d_in[4];
    const float* Wv = (const float*)d_in[5];
    const float* bv = (const float*)d_in[6];
    float* out = (float*)d_out;
    char* ws = (char*)d_ws;
    const size_t MB = 1u << 20;

    // layout (236 MB):
    // [0,6) Wh[3]  [6,12) Wl[3]  [12,44) Qh (f16, single)  [44,76) spare
    // [76,108) Kh  [108,140) Kl  [140,172) Vt  [172,236) Sb f32 [4][S][S]
    // Xh (32 MB f16) aliases Sb's first half [172,204) — dead before scores.
    _Float16* Wh = (_Float16*)ws;          _Float16* Wl = (_Float16*)(ws + 6 * MB);
    _Float16* Qh = (_Float16*)(ws + 12 * MB);
    _Float16* Kh = (_Float16*)(ws + 76 * MB);  _Float16* Kl = (_Float16*)(ws + 108 * MB);
    _Float16* Vt = (_Float16*)(ws + 140 * MB);
    float*    Sb = (float*)(ws + 172 * MB);
    _Float16* Xh = (_Float16*)(ws + 172 * MB);

    const int LDS_T2 = 98304;    // 2 bufs x (1A + 2B) x 16K
    const int LDS_T1 = 98304;    // 2 bufs x (2A x 16K + 2B x 8K)
    hipFuncSetAttribute(reinterpret_cast<const void*>(&bgemm256<2, CM_F16, 256>),
                        hipFuncAttributeMaxDynamicSharedMemorySize, LDS_T2);
    hipFuncSetAttribute(reinterpret_cast<const void*>(&bgemm256<2, CM_SPLIT, 256>),
                        hipFuncAttributeMaxDynamicSharedMemorySize, LDS_T2);
    hipFuncSetAttribute(reinterpret_cast<const void*>(&bgemm256<2, CM_TRANSV, 256>),
                        hipFuncAttributeMaxDynamicSharedMemorySize, LDS_T2);
    hipFuncSetAttribute(reinterpret_cast<const void*>(&bgemm256<2, CM_F32, 256>),
                        hipFuncAttributeMaxDynamicSharedMemorySize, LDS_T2);
    hipFuncSetAttribute(reinterpret_cast<const void*>(&bgemm256<1, CM_F32, 128>),
                        hipFuncAttributeMaxDynamicSharedMemorySize, LDS_T1);

    // 1) convert X -> f16 single plane; W -> f16 hi/lo split (transposed)
    xsplit<<<dim3(8192), 256, 0, stream>>>(X, Xh);
    wsplit<<<dim3(32, 32, 3), dim3(32, 8), 0, stream>>>(Wq, Wk, Wv, Wh, Wl);

    // 2) projections: 2-term fp16 (Xh * (Wh + Wl)).
    //    Q -> single f16 (scores uses only Qh); K -> h/l split; V -> Vt f16.
    const long MW = 1024 * 1024;
    bgemm256<2, CM_F16, 256><<<dim3(D / 256, 64, 1), 512, LDS_T2, stream>>>(
        Xh, nullptr, 0, Wh, Wl, 0, D, D, Qh, nullptr, D, 0, bq, D);
    bgemm256<2, CM_SPLIT, 256><<<dim3(D / 256, 64, 1), 512, LDS_T2, stream>>>(
        Xh, nullptr, 0, Wh + MW, Wl + MW, 0, D, D, Kh, Kl, D, 0, bk, D);
    bgemm256<2, CM_TRANSV, 256><<<dim3(D / 256, 64, 1), 512, LDS_T2, stream>>>(
        Xh, nullptr, 0, Wh + 2 * MW, Wl + 2 * MW, 0, D, D, Vt, nullptr, 0, 0, bv, D);

    // 3) per 4-batch group: scores (2-term: Qh*(Kh+Kl)) -> softmax->f16 P -> PV
    for (int g = 0; g < 2; ++g) {
        const int b0 = g * 4;
        bgemm256<2, CM_F32, 256><<<dim3(S / 256, S / 256, 4), 512, LDS_T2, stream>>>(
            Qh + (long)b0 * S * D, nullptr, (long)S * D,
            Kh + (long)b0 * S * D, Kl + (long)b0 * S * D, (long)S * D,
            D, D, Sb, nullptr, S, (long)S * S, nullptr, D);
        pconv<<<dim3(4 * S), 256, 0, stream>>>(Sb);
        // PV: A = f16 P rows embedded in f32 buffer (lda = 2S f16 elements)
        bgemm256<1, CM_F32, 128><<<dim3(D / 128, S / 256, 4), 512, LDS_T1, stream>>>(
            (const _Float16*)Sb, nullptr, 2L * S * S,
            Vt + (long)b0 * D * S, nullptr, (long)D * S,
            2 * S, S, out + (long)b0 * S * D, nullptr, D, (long)S * D, nullptr, S);
    }
}

// Round 15
// 430.967 us; speedup vs baseline: 1.9324x; 1.0579x over previous
//
#include <hip/hip_runtime.h>
#include <hip/hip_bf16.h>

// B=8, S=2048, D=1024, fp32 in/out.
static constexpr int S = 2048;
static constexpr int D = 1024;
static constexpr int NB = 8;

#define LOG2E 1.4426950408889634f

typedef float    f32x4  __attribute__((ext_vector_type(4)));
typedef _Float16 f16x4  __attribute__((ext_vector_type(4)));
typedef _Float16 f16x8  __attribute__((ext_vector_type(8)));

#define CM_F32    0
#define CM_SPLIT  1
#define CM_TRANSV 2
#define CM_F16    3

#define GLD16(g, l) __builtin_amdgcn_global_load_lds(                         \
    (const __attribute__((address_space(1))) void*)(g),                       \
    (__attribute__((address_space(3))) void*)(l), 16, 0, 0)

#define MFMA16(a, b, c) __builtin_amdgcn_mfma_f32_16x16x32_f16((a), (b), (c), 0, 0, 0)
#define BAR() __builtin_amdgcn_s_barrier()
#define PRIO1() __builtin_amdgcn_s_setprio(1)
#define PRIO0() __builtin_amdgcn_s_setprio(0)
#define WAIT_LGKM(n) asm volatile("s_waitcnt lgkmcnt(" #n ")" ::: "memory")
#define WAIT_VM(n)   asm volatile("s_waitcnt vmcnt(" #n ")" ::: "memory")

// ---------------------------------------------------------------------------
// fp16 GEMM family, 256xBNT tile, 8 waves, never-drain counted pipeline (r10).
//   TERMS==2 (proj, BNT=256): 2-term (A*Bh + A*Bl), A single plane,
//     4 phases, 3 barriers/tile. FIFO: vm(4)@P0 (retires Bl(t)), vm(2)@P2
//     (retires A,Bh(t+1)), lgkm(4)@P0, (4)@P1, (0)@P2 — no in-loop drain.
//   TERMS==1 (scores + PV, BNT=128): 1-term, K-tile 64 (k-half planes),
//     2 phases; seals vm(3)+BAR; lgkm(8)/lgkm(0).
// LDS planes [rows][64B], 4-slot XOR swizzle (slot = chunk ^ ((row>>1)&3)),
// both sides, 0-conflict (verified r10). XCD-bijective block swizzle kept.
// Epilogues: CM_F32 | CM_SPLIT (f16 h+l) | CM_TRANSV (Vt[b][d][s]) | CM_F16.
// ---------------------------------------------------------------------------
template <int TERMS, int CMODE, int BNT>
__global__ __launch_bounds__(512, 1) void bgemm256(
    const _Float16* __restrict__ Ah_, const _Float16* __restrict__ Al_, long sAz,
    const _Float16* __restrict__ Bh_, const _Float16* __restrict__ Bl_, long sBz,
    int lda, int ldb,
    void* __restrict__ C1, void* __restrict__ C2, int ldc, long sCz,
    const float* __restrict__ bias, int K)
{
    extern __shared__ char smem[];
    constexpr int NW_N  = BNT / 64;
    constexpr int NW_M  = 8 / NW_N;
    constexpr int WM    = 256 / NW_M;
    constexpr int MI    = WM / 16;
    constexpr int APLANE = 16384;            // 256 rows x 64 B
    constexpr int BPLANE = BNT * 64;
    constexpr int NAP    = (TERMS == 2) ? 1 : 2;   // A planes per buffer
    constexpr int BOFF   = NAP * APLANE;
    constexpr int BUFSZ  = NAP * APLANE + 2 * BPLANE;

    // ---- XCD-aware bijective block swizzle (T1, m204) ----
    int bx, by, bz;
    {
        const int gx = gridDim.x, gy = gridDim.y;
        const int nwg = gx * gy * gridDim.z;
        const int wg = blockIdx.x + gx * (blockIdx.y + gy * blockIdx.z);
        const int q = nwg >> 3, r = nwg & 7;
        const int xcd = wg & 7, i = wg >> 3;
        const int nid = (xcd < r) ? xcd * (q + 1) + i
                                  : r * (q + 1) + (xcd - r) * q + i;
        bx = nid % gx;
        const int tmp = nid / gx;
        by = tmp % gy;
        bz = tmp / gy;
    }

    const int t = threadIdx.x;
    const int z = bz;
    const int m0 = by * 256;
    const int n0 = bx * BNT;
    const int lane = t & 63, wid = t >> 6;
    const int wr = wid / NW_N, wc = wid % NW_N;
    const int fr = lane & 15, fq = lane >> 4;
    const int lrow = lane >> 2, lslot = lane & 3;

    const _Float16* Ahz = Ah_ + (long)z * sAz;
    const _Float16* Bhz = Bh_ + (long)z * sBz;
    const _Float16* Blz = (TERMS == 2) ? Bl_ + (long)z * sBz : nullptr;

    // stage plane p (T2: p=0 only; T1: k-half p)
    auto stA = [&](int tile, int p) {
        const _Float16* plane = Ahz;
        char* lbase = smem + (tile & 1) * BUFSZ + p * APLANE;
#pragma unroll
        for (int i = 0; i < 2; ++i) {
            const int row = wid * 32 + i * 16 + lrow;
            const int chunk = lslot ^ ((row >> 1) & 3);
            const long kk = (TERMS == 1) ? (long)tile * 64 + p * 32 + chunk * 8
                                         : (long)tile * 32 + chunk * 8;
            GLD16(plane + (long)(m0 + row) * lda + kk,
                  lbase + (wid * 32 + i * 16) * 64);
        }
    };
    auto stB = [&](int tile, int p) {
        const _Float16* plane = (TERMS == 2 && p) ? Blz : Bhz;
        char* lbase = smem + (tile & 1) * BUFSZ + BOFF + p * BPLANE;
        if (TERMS == 2) {
#pragma unroll
            for (int i = 0; i < 2; ++i) {
                const int row = wid * 32 + i * 16 + lrow;
                const int chunk = lslot ^ ((row >> 1) & 3);
                const long kk = (long)tile * 32 + chunk * 8;
                GLD16(plane + (long)(n0 + row) * ldb + kk,
                      lbase + (wid * 32 + i * 16) * 64);
            }
        } else {
            const int row = wid * 16 + lrow;
            const int chunk = lslot ^ ((row >> 1) & 3);
            const long kk = (long)tile * 64 + p * 32 + chunk * 8;
            GLD16(plane + (long)(n0 + row) * ldb + kk, lbase + (wid * 16) * 64);
        }
    };
    auto rdA = [&](int buf, int p, int mi) -> f16x8 {
        const int row = wr * WM + mi * 16 + fr;
        const int slot = fq ^ ((row >> 1) & 3);
        return *(const f16x8*)(smem + buf * BUFSZ + p * APLANE +
                               row * 64 + slot * 16);
    };
    auto rdB = [&](int buf, int p, int ni) -> f16x8 {
        const int row = wc * 64 + ni * 16 + fr;
        const int slot = fq ^ ((row >> 1) & 3);
        return *(const f16x8*)(smem + buf * BUFSZ + BOFF + p * BPLANE +
                               row * 64 + slot * 16);
    };

    f32x4 acc[MI][4] = {};
    const int ktiles = K / ((TERMS == 1) ? 64 : 32);

    if constexpr (TERMS == 2) {
        f16x8 b0h[4], b0l[4], aA[4], aB[4];
        auto mb = [&](int base, f16x8 (&A)[4], f16x8 (&B)[4]) {
#pragma unroll
            for (int mi = 0; mi < 4; ++mi)
#pragma unroll
                for (int ni = 0; ni < 4; ++ni)
                    acc[base + mi][ni] = MFMA16(A[mi], B[ni], acc[base + mi][ni]);
        };
        stA(0, 0); stB(0, 0); stB(0, 1);
        WAIT_VM(0);
        BAR();
#pragma unroll
        for (int ni = 0; ni < 4; ++ni) b0h[ni] = rdB(0, 0, ni);
#pragma unroll
        for (int mi = 0; mi < 4; ++mi) aA[mi] = rdA(0, 0, mi);
#pragma unroll
        for (int mi = 0; mi < 4; ++mi) aB[mi] = rdA(0, 0, 4 + mi);

        for (int tt = 0; tt < ktiles; ++tt) {
            const int buf = tt & 1;
            const bool pf = (tt + 1 < ktiles);
            // P0: stage A,Bh(t+1); vm(4) retires Bl(t); BAR seals B-lo plane
            if (pf) { stA(tt + 1, 0); stB(tt + 1, 0); WAIT_VM(4); }
            else    { WAIT_VM(0); }
            BAR();
            WAIT_LGKM(4);                         // b0h,aA landed (aB left)
            PRIO1(); mb(0, aA, b0h); PRIO0();
            // P1: stage Bl(t+1); pre-read b0l
            if (pf) stB(tt + 1, 1);
#pragma unroll
            for (int ni = 0; ni < 4; ++ni) b0l[ni] = rdB(buf, 1, ni);
            WAIT_LGKM(4);                         // aB landed (b0l left)
            PRIO1(); mb(4, aB, b0h); PRIO0();
            // P2: vm(2) retires A,Bh(t+1); BAR seals them for tail reads
            if (pf) WAIT_VM(2);
            BAR();
            WAIT_LGKM(0);                         // b0l landed
            PRIO1(); mb(0, aA, b0l); PRIO0();
            // P3
            PRIO1(); mb(4, aB, b0l); PRIO0();
            if (pf) {
                const int nb = buf ^ 1;
#pragma unroll
                for (int ni = 0; ni < 4; ++ni) b0h[ni] = rdB(nb, 0, ni);
#pragma unroll
                for (int mi = 0; mi < 4; ++mi) aA[mi] = rdA(nb, 0, mi);
#pragma unroll
                for (int mi = 0; mi < 4; ++mi) aB[mi] = rdA(nb, 0, 4 + mi);
            }
            BAR();
        }
    } else {  // TERMS == 1 (scores + PV, BNT=128, MI=4)
        f16x8 b0[4], b1[4], a0[4], a1[4];
        auto mb = [&](f16x8 (&A)[4], f16x8 (&B)[4]) {
#pragma unroll
            for (int mi = 0; mi < 4; ++mi)
#pragma unroll
                for (int ni = 0; ni < 4; ++ni)
                    acc[mi][ni] = MFMA16(A[mi], B[ni], acc[mi][ni]);
        };
        stA(0, 0); stB(0, 0); stA(0, 1); stB(0, 1);
        WAIT_VM(0);
        BAR();
#pragma unroll
        for (int ni = 0; ni < 4; ++ni) b0[ni] = rdB(0, 0, ni);
#pragma unroll
        for (int mi = 0; mi < 4; ++mi) a0[mi] = rdA(0, 0, mi);

        for (int tt = 0; tt < ktiles; ++tt) {
            const int buf = tt & 1;
            const bool pf = (tt + 1 < ktiles);
            // P0
            if (pf) { stA(tt + 1, 0); stB(tt + 1, 0); WAIT_VM(3); }
            else    { WAIT_VM(0); }
            BAR();
#pragma unroll
            for (int ni = 0; ni < 4; ++ni) b1[ni] = rdB(buf, 1, ni);
#pragma unroll
            for (int mi = 0; mi < 4; ++mi) a1[mi] = rdA(buf, 1, mi);
            WAIT_LGKM(8);
            PRIO1(); mb(a0, b0); PRIO0();
            BAR();
            // P1
            if (pf) { stA(tt + 1, 1); stB(tt + 1, 1); WAIT_VM(3); }
            WAIT_LGKM(0);
            BAR();
            PRIO1(); mb(a1, b1); PRIO0();
            if (pf) {
                const int nb = buf ^ 1;
#pragma unroll
                for (int ni = 0; ni < 4; ++ni) b0[ni] = rdB(nb, 0, ni);
#pragma unroll
                for (int mi = 0; mi < 4; ++mi) a0[mi] = rdA(nb, 0, mi);
            }
        }
    }

    // ---------------- epilogue ----------------
#pragma unroll
    for (int mi = 0; mi < MI; ++mi) {
        const int rbase = m0 + wr * WM + mi * 16 + fq * 4;
#pragma unroll
        for (int ni = 0; ni < 4; ++ni) {
            const int col = n0 + wc * 64 + ni * 16 + fr;
            f32x4 a = acc[mi][ni];
            if (CMODE != CM_F32) {
                const float bv = bias[col];
#pragma unroll
                for (int j = 0; j < 4; ++j) a[j] += bv;
            }
            if (CMODE == CM_F32) {
                float* C = (float*)C1 + (long)z * sCz;
#pragma unroll
                for (int j = 0; j < 4; ++j)
                    C[(long)(rbase + j) * ldc + col] = a[j];
            } else if (CMODE == CM_F16) {
                _Float16* Ch = (_Float16*)C1;
#pragma unroll
                for (int j = 0; j < 4; ++j)
                    Ch[(long)(rbase + j) * ldc + col] = (_Float16)a[j];
            } else if (CMODE == CM_SPLIT) {
                _Float16* Ch = (_Float16*)C1;
                _Float16* Cl = (_Float16*)C2;
#pragma unroll
                for (int j = 0; j < 4; ++j) {
                    const float q = a[j];
                    const _Float16 h = (_Float16)q;
                    Ch[(long)(rbase + j) * ldc + col] = h;
                    Cl[(long)(rbase + j) * ldc + col] = (_Float16)(q - (float)h);
                }
            } else {  // CM_TRANSV: Vt[b][col][s] f16
                const int b_ = rbase >> 11;
                const int s_ = rbase & (S - 1);
                f16x4 h;
#pragma unroll
                for (int j = 0; j < 4; ++j) h[j] = (_Float16)a[j];
                *(f16x4*)((_Float16*)C1 + ((long)b_ * D + col) * S + s_) = h;
            }
        }
    }
}

// ---------------------------------------------------------------------------
// X -> single fp16 plane.
__global__ __launch_bounds__(256) void xsplit(
    const float* __restrict__ X, _Float16* __restrict__ Xh)
{
    const long i = ((long)blockIdx.x * 256 + threadIdx.x) * 8;
    f32x4 v0 = *(const f32x4*)(X + i);
    f32x4 v1 = *(const f32x4*)(X + i + 4);
    f16x8 h;
#pragma unroll
    for (int j = 0; j < 4; ++j) { h[j] = (_Float16)v0[j]; h[4 + j] = (_Float16)v1[j]; }
    *(f16x8*)(Xh + i) = h;
}

// ---------------------------------------------------------------------------
__global__ void wsplit(const float* __restrict__ W0, const float* __restrict__ W1,
                       const float* __restrict__ W2,
                       _Float16* __restrict__ Th, _Float16* __restrict__ Tl)
{
    const float* W = blockIdx.z == 0 ? W0 : (blockIdx.z == 1 ? W1 : W2);
    _Float16* th = Th + (long)blockIdx.z * 1024 * 1024;
    _Float16* tl = Tl + (long)blockIdx.z * 1024 * 1024;
    __shared__ float tile[32][33];
    const int bx = blockIdx.x * 32, by = blockIdx.y * 32;
    const int tx = threadIdx.x, ty = threadIdx.y;
#pragma unroll
    for (int i = ty; i < 32; i += 8) tile[i][tx] = W[(long)(by + i) * 1024 + bx + tx];
    __syncthreads();
#pragma unroll
    for (int i = ty; i < 32; i += 8) {
        const float v = tile[tx][i];
        const _Float16 h = (_Float16)v;
        th[(long)(bx + i) * 1024 + by + tx] = h;
        tl[(long)(bx + i) * 1024 + by + tx] = (_Float16)(v - (float)h);
    }
}

// ---------------------------------------------------------------------------
// Fused row softmax: f32 score row -> P = exp(s-m)/l as fp16, in-place.
__global__ __launch_bounds__(256) void pconv(float* __restrict__ Sb)
{
    const long row = blockIdx.x;
    float* p = Sb + row * (long)S;
    const int t = threadIdx.x;

    f32x4 x0 = *(const f32x4*)(p + t * 8);
    f32x4 x1 = *(const f32x4*)(p + t * 8 + 4);

    float m = -3.4e38f;
#pragma unroll
    for (int j = 0; j < 4; ++j) m = fmaxf(m, fmaxf(x0[j], x1[j]));
#pragma unroll
    for (int o = 32; o >= 1; o >>= 1) m = fmaxf(m, __shfl_xor(m, o));

    __shared__ float wm[4], wsum[4];
    const int wid = t >> 6, lane = t & 63;
    if (lane == 0) wm[wid] = m;
    __syncthreads();
    m = fmaxf(fmaxf(wm[0], wm[1]), fmaxf(wm[2], wm[3]));

    float e[8], ssum = 0.f;
#pragma unroll
    for (int j = 0; j < 4; ++j) {
        e[j]     = exp2f((x0[j] - m) * LOG2E);
        e[4 + j] = exp2f((x1[j] - m) * LOG2E);
        ssum += e[j] + e[4 + j];
    }
#pragma unroll
    for (int o = 32; o >= 1; o >>= 1) ssum += __shfl_xor(ssum, o);
    if (lane == 0) wsum[wid] = ssum;
    __syncthreads();
    const float invl = 1.0f / (wsum[0] + wsum[1] + wsum[2] + wsum[3]);

    f16x8 outv;
#pragma unroll
    for (int j = 0; j < 8; ++j) outv[j] = (_Float16)(e[j] * invl);
    *(f16x8*)((_Float16*)p + t * 8) = outv;
}

// ---------------------------------------------------------------------------
extern "C" void kernel_launch(void* const* d_in, const int* in_sizes, int n_in,
                              void* d_out, int out_size, void* d_ws, size_t ws_size,
                              hipStream_t stream)
{
    const float* X  = (const float*)d_in[0];
    const float* Wq = (const float*)d_in[1];
    const float* bq = (const float*)d_in[2];
    const float* Wk = (const float*)d_in[3];
    const float* bk = (const float*)d_in[4];
    const float* Wv = (const float*)d_in[5];
    const float* bv = (const float*)d_in[6];
    float* out = (float*)d_out;
    char* ws = (char*)d_ws;
    const size_t MB = 1u << 20;

    // layout (236 MB):
    // [0,6) Wh[3]  [6,12) Wl[3]  [12,44) Qh f16  [44,76) spare
    // [76,108) Kh f16  [108,140) spare  [140,172) Vt f16
    // [172,236) Sb f32 [4][S][S] (P f16 in-place)
    // Xh (32 MB f16) aliases Sb's first half [172,204) — dead before scores.
    _Float16* Wh = (_Float16*)ws;          _Float16* Wl = (_Float16*)(ws + 6 * MB);
    _Float16* Qh = (_Float16*)(ws + 12 * MB);
    _Float16* Kh = (_Float16*)(ws + 76 * MB);
    _Float16* Vt = (_Float16*)(ws + 140 * MB);
    float*    Sb = (float*)(ws + 172 * MB);
    _Float16* Xh = (_Float16*)(ws + 172 * MB);

    const int LDS_T2 = 98304;    // 2 bufs x (1A + 2B) x 16K
    const int LDS_T1 = 98304;    // 2 bufs x (2A x 16K + 2B x 8K)
    hipFuncSetAttribute(reinterpret_cast<const void*>(&bgemm256<2, CM_F16, 256>),
                        hipFuncAttributeMaxDynamicSharedMemorySize, LDS_T2);
    hipFuncSetAttribute(reinterpret_cast<const void*>(&bgemm256<2, CM_TRANSV, 256>),
                        hipFuncAttributeMaxDynamicSharedMemorySize, LDS_T2);
    hipFuncSetAttribute(reinterpret_cast<const void*>(&bgemm256<1, CM_F32, 128>),
                        hipFuncAttributeMaxDynamicSharedMemorySize, LDS_T1);

    // 1) convert X -> f16 single plane; W -> f16 hi/lo split (transposed)
    xsplit<<<dim3(8192), 256, 0, stream>>>(X, Xh);
    wsplit<<<dim3(32, 32, 3), dim3(32, 8), 0, stream>>>(Wq, Wk, Wv, Wh, Wl);

    // 2) projections: 2-term fp16 (Xh * (Wh + Wl)); Q,K single f16; V -> Vt.
    const long MW = 1024 * 1024;
    bgemm256<2, CM_F16, 256><<<dim3(D / 256, 64, 1), 512, LDS_T2, stream>>>(
        Xh, nullptr, 0, Wh, Wl, 0, D, D, Qh, nullptr, D, 0, bq, D);
    bgemm256<2, CM_F16, 256><<<dim3(D / 256, 64, 1), 512, LDS_T2, stream>>>(
        Xh, nullptr, 0, Wh + MW, Wl + MW, 0, D, D, Kh, nullptr, D, 0, bk, D);
    bgemm256<2, CM_TRANSV, 256><<<dim3(D / 256, 64, 1), 512, LDS_T2, stream>>>(
        Xh, nullptr, 0, Wh + 2 * MW, Wl + 2 * MW, 0, D, D, Vt, nullptr, 0, 0, bv, D);

    // 3) per 4-batch group: scores (1-term Qh*Kh) -> softmax->f16 P -> PV
    for (int g = 0; g < 2; ++g) {
        const int b0 = g * 4;
        bgemm256<1, CM_F32, 128><<<dim3(S / 128, S / 256, 4), 512, LDS_T1, stream>>>(
            Qh + (long)b0 * S * D, nullptr, (long)S * D,
            Kh + (long)b0 * S * D, nullptr, (long)S * D,
            D, D, Sb, nullptr, S, (long)S * S, nullptr, D);
        pconv<<<dim3(4 * S), 256, 0, stream>>>(Sb);
        // PV: A = f16 P rows embedded in f32 buffer (lda = 2S f16 elements)
        bgemm256<1, CM_F32, 128><<<dim3(D / 128, S / 256, 4), 512, LDS_T1, stream>>>(
            (const _Float16*)Sb, nullptr, 2L * S * S,
            Vt + (long)b0 * D * S, nullptr, (long)D * S,
            2 * S, S, out + (long)b0 * S * D, nullptr, D, (long)S * D, nullptr, S);
    }
}

// Round 16
// 377.570 us; speedup vs baseline: 2.2057x; 1.1414x over previous
//
#include <hip/hip_runtime.h>
#include <hip/hip_bf16.h>

// B=8, S=2048, D=1024, fp32 in/out.
static constexpr int S = 2048;
static constexpr int D = 1024;
static constexpr int NB = 8;

#define LOG2E 1.4426950408889634f

typedef float    f32x4  __attribute__((ext_vector_type(4)));
typedef _Float16 f16x4  __attribute__((ext_vector_type(4)));
typedef _Float16 f16x8  __attribute__((ext_vector_type(8)));

#define CM_F32    0
#define CM_SPLIT  1
#define CM_TRANSV 2
#define CM_F16    3

#define GLD16(g, l) __builtin_amdgcn_global_load_lds(                         \
    (const __attribute__((address_space(1))) void*)(g),                       \
    (__attribute__((address_space(3))) void*)(l), 16, 0, 0)

#define MFMA16(a, b, c) __builtin_amdgcn_mfma_f32_16x16x32_f16((a), (b), (c), 0, 0, 0)
#define BAR() __builtin_amdgcn_s_barrier()
#define PRIO1() __builtin_amdgcn_s_setprio(1)
#define PRIO0() __builtin_amdgcn_s_setprio(0)
#define WAIT_LGKM(n) asm volatile("s_waitcnt lgkmcnt(" #n ")" ::: "memory")
#define WAIT_VM(n)   asm volatile("s_waitcnt vmcnt(" #n ")" ::: "memory")

// ---------------------------------------------------------------------------
// fp16 GEMM family, 256xBNT tile, 8 waves, never-drain counted pipeline (r10).
//   TERMS==1 (proj + scores + PV, BNT=128): 1-term C = A*B, K-tile 64
//     (k-half planes), 2 phases; seals vm(3)+BAR; lgkm(8)/lgkm(0).
//   (TERMS==2 path retained but no longer instantiated.)
// LDS planes [rows][64B], 4-slot XOR swizzle (slot = chunk ^ ((row>>1)&3)),
// both sides, 0-conflict (verified r10). XCD-bijective block swizzle kept.
// Epilogues: CM_F32 | CM_F16 | CM_TRANSV (Vt[b][d][s] f16) | CM_SPLIT.
// ---------------------------------------------------------------------------
template <int TERMS, int CMODE, int BNT>
__global__ __launch_bounds__(512, 1) void bgemm256(
    const _Float16* __restrict__ Ah_, const _Float16* __restrict__ Al_, long sAz,
    const _Float16* __restrict__ Bh_, const _Float16* __restrict__ Bl_, long sBz,
    int lda, int ldb,
    void* __restrict__ C1, void* __restrict__ C2, int ldc, long sCz,
    const float* __restrict__ bias, int K)
{
    extern __shared__ char smem[];
    constexpr int NW_N  = BNT / 64;
    constexpr int NW_M  = 8 / NW_N;
    constexpr int WM    = 256 / NW_M;
    constexpr int MI    = WM / 16;
    constexpr int APLANE = 16384;            // 256 rows x 64 B
    constexpr int BPLANE = BNT * 64;
    constexpr int NAP    = (TERMS == 2) ? 1 : 2;   // A planes per buffer
    constexpr int BOFF   = NAP * APLANE;
    constexpr int BUFSZ  = NAP * APLANE + 2 * BPLANE;

    // ---- XCD-aware bijective block swizzle (T1, m204) ----
    int bx, by, bz;
    {
        const int gx = gridDim.x, gy = gridDim.y;
        const int nwg = gx * gy * gridDim.z;
        const int wg = blockIdx.x + gx * (blockIdx.y + gy * blockIdx.z);
        const int q = nwg >> 3, r = nwg & 7;
        const int xcd = wg & 7, i = wg >> 3;
        const int nid = (xcd < r) ? xcd * (q + 1) + i
                                  : r * (q + 1) + (xcd - r) * q + i;
        bx = nid % gx;
        const int tmp = nid / gx;
        by = tmp % gy;
        bz = tmp / gy;
    }

    const int t = threadIdx.x;
    const int z = bz;
    const int m0 = by * 256;
    const int n0 = bx * BNT;
    const int lane = t & 63, wid = t >> 6;
    const int wr = wid / NW_N, wc = wid % NW_N;
    const int fr = lane & 15, fq = lane >> 4;
    const int lrow = lane >> 2, lslot = lane & 3;

    const _Float16* Ahz = Ah_ + (long)z * sAz;
    const _Float16* Bhz = Bh_ + (long)z * sBz;
    const _Float16* Blz = (TERMS == 2) ? Bl_ + (long)z * sBz : nullptr;

    // stage plane p (T2: p=0 only; T1: k-half p)
    auto stA = [&](int tile, int p) {
        const _Float16* plane = Ahz;
        char* lbase = smem + (tile & 1) * BUFSZ + p * APLANE;
#pragma unroll
        for (int i = 0; i < 2; ++i) {
            const int row = wid * 32 + i * 16 + lrow;
            const int chunk = lslot ^ ((row >> 1) & 3);
            const long kk = (TERMS == 1) ? (long)tile * 64 + p * 32 + chunk * 8
                                         : (long)tile * 32 + chunk * 8;
            GLD16(plane + (long)(m0 + row) * lda + kk,
                  lbase + (wid * 32 + i * 16) * 64);
        }
    };
    auto stB = [&](int tile, int p) {
        const _Float16* plane = (TERMS == 2 && p) ? Blz : Bhz;
        char* lbase = smem + (tile & 1) * BUFSZ + BOFF + p * BPLANE;
        if (TERMS == 2) {
#pragma unroll
            for (int i = 0; i < 2; ++i) {
                const int row = wid * 32 + i * 16 + lrow;
                const int chunk = lslot ^ ((row >> 1) & 3);
                const long kk = (long)tile * 32 + chunk * 8;
                GLD16(plane + (long)(n0 + row) * ldb + kk,
                      lbase + (wid * 32 + i * 16) * 64);
            }
        } else {
            const int row = wid * 16 + lrow;
            const int chunk = lslot ^ ((row >> 1) & 3);
            const long kk = (long)tile * 64 + p * 32 + chunk * 8;
            GLD16(plane + (long)(n0 + row) * ldb + kk, lbase + (wid * 16) * 64);
        }
    };
    auto rdA = [&](int buf, int p, int mi) -> f16x8 {
        const int row = wr * WM + mi * 16 + fr;
        const int slot = fq ^ ((row >> 1) & 3);
        return *(const f16x8*)(smem + buf * BUFSZ + p * APLANE +
                               row * 64 + slot * 16);
    };
    auto rdB = [&](int buf, int p, int ni) -> f16x8 {
        const int row = wc * 64 + ni * 16 + fr;
        const int slot = fq ^ ((row >> 1) & 3);
        return *(const f16x8*)(smem + buf * BUFSZ + BOFF + p * BPLANE +
                               row * 64 + slot * 16);
    };

    f32x4 acc[MI][4] = {};
    const int ktiles = K / ((TERMS == 1) ? 64 : 32);

    if constexpr (TERMS == 2) {
        f16x8 b0h[4], b0l[4], aA[4], aB[4];
        auto mb = [&](int base, f16x8 (&A)[4], f16x8 (&B)[4]) {
#pragma unroll
            for (int mi = 0; mi < 4; ++mi)
#pragma unroll
                for (int ni = 0; ni < 4; ++ni)
                    acc[base + mi][ni] = MFMA16(A[mi], B[ni], acc[base + mi][ni]);
        };
        stA(0, 0); stB(0, 0); stB(0, 1);
        WAIT_VM(0);
        BAR();
#pragma unroll
        for (int ni = 0; ni < 4; ++ni) b0h[ni] = rdB(0, 0, ni);
#pragma unroll
        for (int mi = 0; mi < 4; ++mi) aA[mi] = rdA(0, 0, mi);
#pragma unroll
        for (int mi = 0; mi < 4; ++mi) aB[mi] = rdA(0, 0, 4 + mi);

        for (int tt = 0; tt < ktiles; ++tt) {
            const int buf = tt & 1;
            const bool pf = (tt + 1 < ktiles);
            if (pf) { stA(tt + 1, 0); stB(tt + 1, 0); WAIT_VM(4); }
            else    { WAIT_VM(0); }
            BAR();
            WAIT_LGKM(4);
            PRIO1(); mb(0, aA, b0h); PRIO0();
            if (pf) stB(tt + 1, 1);
#pragma unroll
            for (int ni = 0; ni < 4; ++ni) b0l[ni] = rdB(buf, 1, ni);
            WAIT_LGKM(4);
            PRIO1(); mb(4, aB, b0h); PRIO0();
            if (pf) WAIT_VM(2);
            BAR();
            WAIT_LGKM(0);
            PRIO1(); mb(0, aA, b0l); PRIO0();
            PRIO1(); mb(4, aB, b0l); PRIO0();
            if (pf) {
                const int nb = buf ^ 1;
#pragma unroll
                for (int ni = 0; ni < 4; ++ni) b0h[ni] = rdB(nb, 0, ni);
#pragma unroll
                for (int mi = 0; mi < 4; ++mi) aA[mi] = rdA(nb, 0, mi);
#pragma unroll
                for (int mi = 0; mi < 4; ++mi) aB[mi] = rdA(nb, 0, 4 + mi);
            }
            BAR();
        }
    } else {  // TERMS == 1 (proj + scores + PV, BNT=128, MI=4)
        f16x8 b0[4], b1[4], a0[4], a1[4];
        auto mb = [&](f16x8 (&A)[4], f16x8 (&B)[4]) {
#pragma unroll
            for (int mi = 0; mi < 4; ++mi)
#pragma unroll
                for (int ni = 0; ni < 4; ++ni)
                    acc[mi][ni] = MFMA16(A[mi], B[ni], acc[mi][ni]);
        };
        stA(0, 0); stB(0, 0); stA(0, 1); stB(0, 1);
        WAIT_VM(0);
        BAR();
#pragma unroll
        for (int ni = 0; ni < 4; ++ni) b0[ni] = rdB(0, 0, ni);
#pragma unroll
        for (int mi = 0; mi < 4; ++mi) a0[mi] = rdA(0, 0, mi);

        for (int tt = 0; tt < ktiles; ++tt) {
            const int buf = tt & 1;
            const bool pf = (tt + 1 < ktiles);
            // P0
            if (pf) { stA(tt + 1, 0); stB(tt + 1, 0); WAIT_VM(3); }
            else    { WAIT_VM(0); }
            BAR();
#pragma unroll
            for (int ni = 0; ni < 4; ++ni) b1[ni] = rdB(buf, 1, ni);
#pragma unroll
            for (int mi = 0; mi < 4; ++mi) a1[mi] = rdA(buf, 1, mi);
            WAIT_LGKM(8);
            PRIO1(); mb(a0, b0); PRIO0();
            BAR();
            // P1
            if (pf) { stA(tt + 1, 1); stB(tt + 1, 1); WAIT_VM(3); }
            WAIT_LGKM(0);
            BAR();
            PRIO1(); mb(a1, b1); PRIO0();
            if (pf) {
                const int nb = buf ^ 1;
#pragma unroll
                for (int ni = 0; ni < 4; ++ni) b0[ni] = rdB(nb, 0, ni);
#pragma unroll
                for (int mi = 0; mi < 4; ++mi) a0[mi] = rdA(nb, 0, mi);
            }
        }
    }

    // ---------------- epilogue ----------------
#pragma unroll
    for (int mi = 0; mi < MI; ++mi) {
        const int rbase = m0 + wr * WM + mi * 16 + fq * 4;
#pragma unroll
        for (int ni = 0; ni < 4; ++ni) {
            const int col = n0 + wc * 64 + ni * 16 + fr;
            f32x4 a = acc[mi][ni];
            if (CMODE != CM_F32) {
                const float bv = bias[col];
#pragma unroll
                for (int j = 0; j < 4; ++j) a[j] += bv;
            }
            if (CMODE == CM_F32) {
                float* C = (float*)C1 + (long)z * sCz;
#pragma unroll
                for (int j = 0; j < 4; ++j)
                    C[(long)(rbase + j) * ldc + col] = a[j];
            } else if (CMODE == CM_F16) {
                _Float16* Ch = (_Float16*)C1;
#pragma unroll
                for (int j = 0; j < 4; ++j)
                    Ch[(long)(rbase + j) * ldc + col] = (_Float16)a[j];
            } else if (CMODE == CM_SPLIT) {
                _Float16* Ch = (_Float16*)C1;
                _Float16* Cl = (_Float16*)C2;
#pragma unroll
                for (int j = 0; j < 4; ++j) {
                    const float q = a[j];
                    const _Float16 h = (_Float16)q;
                    Ch[(long)(rbase + j) * ldc + col] = h;
                    Cl[(long)(rbase + j) * ldc + col] = (_Float16)(q - (float)h);
                }
            } else {  // CM_TRANSV: Vt[b][col][s] f16
                const int b_ = rbase >> 11;
                const int s_ = rbase & (S - 1);
                f16x4 h;
#pragma unroll
                for (int j = 0; j < 4; ++j) h[j] = (_Float16)a[j];
                *(f16x4*)((_Float16*)C1 + ((long)b_ * D + col) * S + s_) = h;
            }
        }
    }
}

// ---------------------------------------------------------------------------
// X -> single fp16 plane.
__global__ __launch_bounds__(256) void xsplit(
    const float* __restrict__ X, _Float16* __restrict__ Xh)
{
    const long i = ((long)blockIdx.x * 256 + threadIdx.x) * 8;
    f32x4 v0 = *(const f32x4*)(X + i);
    f32x4 v1 = *(const f32x4*)(X + i + 4);
    f16x8 h;
#pragma unroll
    for (int j = 0; j < 4; ++j) { h[j] = (_Float16)v0[j]; h[4 + j] = (_Float16)v1[j]; }
    *(f16x8*)(Xh + i) = h;
}

// ---------------------------------------------------------------------------
// Transpose 1024x1024 W -> single f16 plane (1-term projections).
__global__ void wsplit(const float* __restrict__ W0, const float* __restrict__ W1,
                       const float* __restrict__ W2, _Float16* __restrict__ Th)
{
    const float* W = blockIdx.z == 0 ? W0 : (blockIdx.z == 1 ? W1 : W2);
    _Float16* th = Th + (long)blockIdx.z * 1024 * 1024;
    __shared__ float tile[32][33];
    const int bx = blockIdx.x * 32, by = blockIdx.y * 32;
    const int tx = threadIdx.x, ty = threadIdx.y;
#pragma unroll
    for (int i = ty; i < 32; i += 8) tile[i][tx] = W[(long)(by + i) * 1024 + bx + tx];
    __syncthreads();
#pragma unroll
    for (int i = ty; i < 32; i += 8)
        th[(long)(bx + i) * 1024 + by + tx] = (_Float16)tile[tx][i];
}

// ---------------------------------------------------------------------------
// Fused row softmax: f32 score row -> P = exp(s-m)/l as fp16, in-place.
__global__ __launch_bounds__(256) void pconv(float* __restrict__ Sb)
{
    const long row = blockIdx.x;
    float* p = Sb + row * (long)S;
    const int t = threadIdx.x;

    f32x4 x0 = *(const f32x4*)(p + t * 8);
    f32x4 x1 = *(const f32x4*)(p + t * 8 + 4);

    float m = -3.4e38f;
#pragma unroll
    for (int j = 0; j < 4; ++j) m = fmaxf(m, fmaxf(x0[j], x1[j]));
#pragma unroll
    for (int o = 32; o >= 1; o >>= 1) m = fmaxf(m, __shfl_xor(m, o));

    __shared__ float wm[4], wsum[4];
    const int wid = t >> 6, lane = t & 63;
    if (lane == 0) wm[wid] = m;
    __syncthreads();
    m = fmaxf(fmaxf(wm[0], wm[1]), fmaxf(wm[2], wm[3]));

    float e[8], ssum = 0.f;
#pragma unroll
    for (int j = 0; j < 4; ++j) {
        e[j]     = exp2f((x0[j] - m) * LOG2E);
        e[4 + j] = exp2f((x1[j] - m) * LOG2E);
        ssum += e[j] + e[4 + j];
    }
#pragma unroll
    for (int o = 32; o >= 1; o >>= 1) ssum += __shfl_xor(ssum, o);
    if (lane == 0) wsum[wid] = ssum;
    __syncthreads();
    const float invl = 1.0f / (wsum[0] + wsum[1] + wsum[2] + wsum[3]);

    f16x8 outv;
#pragma unroll
    for (int j = 0; j < 8; ++j) outv[j] = (_Float16)(e[j] * invl);
    *(f16x8*)((_Float16*)p + t * 8) = outv;
}

// ---------------------------------------------------------------------------
extern "C" void kernel_launch(void* const* d_in, const int* in_sizes, int n_in,
                              void* d_out, int out_size, void* d_ws, size_t ws_size,
                              hipStream_t stream)
{
    const float* X  = (const float*)d_in[0];
    const float* Wq = (const float*)d_in[1];
    const float* bq = (const float*)d_in[2];
    const float* Wk = (const float*)d_in[3];
    const float* bk = (const float*)d_in[4];
    const float* Wv = (const float*)d_in[5];
    const float* bv = (const float*)d_in[6];
    float* out = (float*)d_out;
    char* ws = (char*)d_ws;
    const size_t MB = 1u << 20;

    // layout (236 MB):
    // [0,6) Wh[3] f16  [6,12) spare  [12,44) Qh f16  [44,76) spare
    // [76,108) Kh f16  [108,140) spare  [140,172) Vt f16
    // [172,236) Sb f32 [4][S][S] (P f16 in-place)
    // Xh (32 MB f16) aliases Sb's first half [172,204) — dead before scores.
    _Float16* Wh = (_Float16*)ws;
    _Float16* Qh = (_Float16*)(ws + 12 * MB);
    _Float16* Kh = (_Float16*)(ws + 76 * MB);
    _Float16* Vt = (_Float16*)(ws + 140 * MB);
    float*    Sb = (float*)(ws + 172 * MB);
    _Float16* Xh = (_Float16*)(ws + 172 * MB);

    const int LDS_T1 = 98304;    // 2 bufs x (2A x 16K + 2B x 8K)
    hipFuncSetAttribute(reinterpret_cast<const void*>(&bgemm256<1, CM_F16, 128>),
                        hipFuncAttributeMaxDynamicSharedMemorySize, LDS_T1);
    hipFuncSetAttribute(reinterpret_cast<const void*>(&bgemm256<1, CM_TRANSV, 128>),
                        hipFuncAttributeMaxDynamicSharedMemorySize, LDS_T1);
    hipFuncSetAttribute(reinterpret_cast<const void*>(&bgemm256<1, CM_F32, 128>),
                        hipFuncAttributeMaxDynamicSharedMemorySize, LDS_T1);

    // 1) convert X -> f16 single plane; W -> f16 single plane (transposed)
    xsplit<<<dim3(8192), 256, 0, stream>>>(X, Xh);
    wsplit<<<dim3(32, 32, 3), dim3(32, 8), 0, stream>>>(Wq, Wk, Wv, Wh);

    // 2) projections: 1-term fp16 (Xh * Wh); Q,K single f16; V -> Vt f16.
    const long MW = 1024 * 1024;
    bgemm256<1, CM_F16, 128><<<dim3(D / 128, 64, 1), 512, LDS_T1, stream>>>(
        Xh, nullptr, 0, Wh, nullptr, 0, D, D, Qh, nullptr, D, 0, bq, D);
    bgemm256<1, CM_F16, 128><<<dim3(D / 128, 64, 1), 512, LDS_T1, stream>>>(
        Xh, nullptr, 0, Wh + MW, nullptr, 0, D, D, Kh, nullptr, D, 0, bk, D);
    bgemm256<1, CM_TRANSV, 128><<<dim3(D / 128, 64, 1), 512, LDS_T1, stream>>>(
        Xh, nullptr, 0, Wh + 2 * MW, nullptr, 0, D, D, Vt, nullptr, 0, 0, bv, D);

    // 3) per 4-batch group: scores (1-term Qh*Kh) -> softmax->f16 P -> PV
    for (int g = 0; g < 2; ++g) {
        const int b0 = g * 4;
        bgemm256<1, CM_F32, 128><<<dim3(S / 128, S / 256, 4), 512, LDS_T1, stream>>>(
            Qh + (long)b0 * S * D, nullptr, (long)S * D,
            Kh + (long)b0 * S * D, nullptr, (long)S * D,
            D, D, Sb, nullptr, S, (long)S * S, nullptr, D);
        pconv<<<dim3(4 * S), 256, 0, stream>>>(Sb);
        // PV: A = f16 P rows embedded in f32 buffer (lda = 2S f16 elements)
        bgemm256<1, CM_F32, 128><<<dim3(D / 128, S / 256, 4), 512, LDS_T1, stream>>>(
            (const _Float16*)Sb, nullptr, 2L * S * S,
            Vt + (long)b0 * D * S, nullptr, (long)D * S,
            2 * S, S, out + (long)b0 * S * D, nullptr, D, (long)S * D, nullptr, S);
    }
}

// Round 17
// 362.479 us; speedup vs baseline: 2.2975x; 1.0416x over previous
//
#include <hip/hip_runtime.h>
#include <hip/hip_bf16.h>

// B=8, S=2048, D=1024, fp32 in/out.
static constexpr int S = 2048;
static constexpr int D = 1024;
static constexpr int NB = 8;

#define LOG2E 1.4426950408889634f

typedef float    f32x4  __attribute__((ext_vector_type(4)));
typedef _Float16 f16x4  __attribute__((ext_vector_type(4)));
typedef _Float16 f16x8  __attribute__((ext_vector_type(8)));

#define CM_F32    0
#define CM_TRANSV 2
#define CM_F16    3

#define GLD16(g, l) __builtin_amdgcn_global_load_lds(                         \
    (const __attribute__((address_space(1))) void*)(g),                       \
    (__attribute__((address_space(3))) void*)(l), 16, 0, 0)

#define MFMA16(a, b, c) __builtin_amdgcn_mfma_f32_16x16x32_f16((a), (b), (c), 0, 0, 0)
#define BAR() __builtin_amdgcn_s_barrier()
#define PRIO1() __builtin_amdgcn_s_setprio(1)
#define PRIO0() __builtin_amdgcn_s_setprio(0)
#define WAIT_LGKM(n) asm volatile("s_waitcnt lgkmcnt(" #n ")" ::: "memory")
#define WAIT_VM(n)   asm volatile("s_waitcnt vmcnt(" #n ")" ::: "memory")

// ---------------------------------------------------------------------------
// fp16 1-term GEMM (C = A*B^T), 256x128 tile, 8 waves, never-drain counted
// pipeline (r10-verified): K-tile 64 (k-half planes), 2 phases;
// seals vm(3)+BAR; lgkm(8)/lgkm(0). LDS planes [rows][64B], 4-slot XOR
// swizzle (slot = chunk ^ ((row>>1)&3)), both sides, 0-conflict.
// XCD-bijective block swizzle (T1/m204).
// Epilogues: CM_F32 | CM_F16 | CM_TRANSV (LDS-transposed coalesced
// Vt[b][d][s] writes — r17: replaces the 8B-scatter store, bit-identical).
// ---------------------------------------------------------------------------
template <int CMODE>
__global__ __launch_bounds__(512, 1) void bgemm256(
    const _Float16* __restrict__ Ah_, long sAz,
    const _Float16* __restrict__ Bh_, long sBz,
    int lda, int ldb,
    void* __restrict__ C1, int ldc, long sCz,
    const float* __restrict__ bias, int K)
{
    extern __shared__ char smem[];
    constexpr int BNT   = 128;
    constexpr int WM    = 64;                // rows per wave tile (NW_M=4)
    constexpr int MI    = 4;
    constexpr int APLANE = 16384;            // 256 rows x 64 B
    constexpr int BPLANE = BNT * 64;         // 8 KB
    constexpr int BOFF   = 2 * APLANE;
    constexpr int BUFSZ  = 2 * APLANE + 2 * BPLANE;   // 48 KB

    // ---- XCD-aware bijective block swizzle (T1, m204) ----
    int bx, by, bz;
    {
        const int gx = gridDim.x, gy = gridDim.y;
        const int nwg = gx * gy * gridDim.z;
        const int wg = blockIdx.x + gx * (blockIdx.y + gy * blockIdx.z);
        const int q = nwg >> 3, r = nwg & 7;
        const int xcd = wg & 7, i = wg >> 3;
        const int nid = (xcd < r) ? xcd * (q + 1) + i
                                  : r * (q + 1) + (xcd - r) * q + i;
        bx = nid % gx;
        const int tmp = nid / gx;
        by = tmp % gy;
        bz = tmp / gy;
    }

    const int t = threadIdx.x;
    const int z = bz;
    const int m0 = by * 256;
    const int n0 = bx * BNT;
    const int lane = t & 63, wid = t >> 6;
    const int wr = wid >> 1, wc = wid & 1;
    const int fr = lane & 15, fq = lane >> 4;
    const int lrow = lane >> 2, lslot = lane & 3;

    const _Float16* Ahz = Ah_ + (long)z * sAz;
    const _Float16* Bhz = Bh_ + (long)z * sBz;

    auto stA = [&](int tile, int p) {
        char* lbase = smem + (tile & 1) * BUFSZ + p * APLANE;
#pragma unroll
        for (int i = 0; i < 2; ++i) {
            const int row = wid * 32 + i * 16 + lrow;
            const int chunk = lslot ^ ((row >> 1) & 3);
            const long kk = (long)tile * 64 + p * 32 + chunk * 8;
            GLD16(Ahz + (long)(m0 + row) * lda + kk,
                  lbase + (wid * 32 + i * 16) * 64);
        }
    };
    auto stB = [&](int tile, int p) {
        char* lbase = smem + (tile & 1) * BUFSZ + BOFF + p * BPLANE;
        const int row = wid * 16 + lrow;
        const int chunk = lslot ^ ((row >> 1) & 3);
        const long kk = (long)tile * 64 + p * 32 + chunk * 8;
        GLD16(Bhz + (long)(n0 + row) * ldb + kk, lbase + (wid * 16) * 64);
    };
    auto rdA = [&](int buf, int p, int mi) -> f16x8 {
        const int row = wr * WM + mi * 16 + fr;
        const int slot = fq ^ ((row >> 1) & 3);
        return *(const f16x8*)(smem + buf * BUFSZ + p * APLANE +
                               row * 64 + slot * 16);
    };
    auto rdB = [&](int buf, int p, int ni) -> f16x8 {
        const int row = wc * 64 + ni * 16 + fr;
        const int slot = fq ^ ((row >> 1) & 3);
        return *(const f16x8*)(smem + buf * BUFSZ + BOFF + p * BPLANE +
                               row * 64 + slot * 16);
    };

    f32x4 acc[MI][4] = {};
    const int ktiles = K / 64;

    {
        f16x8 b0[4], b1[4], a0[4], a1[4];
        auto mb = [&](f16x8 (&A)[4], f16x8 (&B)[4]) {
#pragma unroll
            for (int mi = 0; mi < 4; ++mi)
#pragma unroll
                for (int ni = 0; ni < 4; ++ni)
                    acc[mi][ni] = MFMA16(A[mi], B[ni], acc[mi][ni]);
        };
        stA(0, 0); stB(0, 0); stA(0, 1); stB(0, 1);
        WAIT_VM(0);
        BAR();
#pragma unroll
        for (int ni = 0; ni < 4; ++ni) b0[ni] = rdB(0, 0, ni);
#pragma unroll
        for (int mi = 0; mi < 4; ++mi) a0[mi] = rdA(0, 0, mi);

        for (int tt = 0; tt < ktiles; ++tt) {
            const int buf = tt & 1;
            const bool pf = (tt + 1 < ktiles);
            // P0
            if (pf) { stA(tt + 1, 0); stB(tt + 1, 0); WAIT_VM(3); }
            else    { WAIT_VM(0); }
            BAR();
#pragma unroll
            for (int ni = 0; ni < 4; ++ni) b1[ni] = rdB(buf, 1, ni);
#pragma unroll
            for (int mi = 0; mi < 4; ++mi) a1[mi] = rdA(buf, 1, mi);
            WAIT_LGKM(8);
            PRIO1(); mb(a0, b0); PRIO0();
            BAR();
            // P1
            if (pf) { stA(tt + 1, 1); stB(tt + 1, 1); WAIT_VM(3); }
            WAIT_LGKM(0);
            BAR();
            PRIO1(); mb(a1, b1); PRIO0();
            if (pf) {
                const int nb = buf ^ 1;
#pragma unroll
                for (int ni = 0; ni < 4; ++ni) b0[ni] = rdB(nb, 0, ni);
#pragma unroll
                for (int mi = 0; mi < 4; ++mi) a0[mi] = rdA(nb, 0, mi);
            }
        }
    }

    // ---------------- epilogue ----------------
    if constexpr (CMODE == CM_TRANSV) {
        // LDS transpose: Tt[128 d][272 f16] (544-B row stride, 16B-aligned).
        // All staging reads retired (in-loop lgkm(0)+BAR); smem reusable.
        constexpr int LDT = 544;
#pragma unroll
        for (int mi = 0; mi < MI; ++mi) {
            const int row0 = wr * WM + mi * 16 + fq * 4;   // 0..255, mult of 4
#pragma unroll
            for (int ni = 0; ni < 4; ++ni) {
                const int colp = wc * 64 + ni * 16 + fr;    // 0..127
                const float bv = bias[n0 + colp];
                f16x4 h;
#pragma unroll
                for (int j = 0; j < 4; ++j) h[j] = (_Float16)(acc[mi][ni][j] + bv);
                *(f16x4*)(smem + colp * LDT + row0 * 2) = h;
            }
        }
        BAR();
        const int b_ = m0 >> 11;             // 2048 rows per batch; tiles don't straddle
        const int sbase = m0 & (S - 1);
        const int l31 = lane & 31, lh = lane >> 5;
        _Float16* Vp = (_Float16*)C1;
#pragma unroll
        for (int it = 0; it < 8; ++it) {
            const int dd = wid * 16 + it * 2 + lh;
            const f16x8 v = *(const f16x8*)(smem + dd * LDT + l31 * 16);
            *(f16x8*)(Vp + ((long)(b_ * D + n0 + dd)) * S + sbase + l31 * 8) = v;
        }
    } else {
#pragma unroll
        for (int mi = 0; mi < MI; ++mi) {
            const int rbase = m0 + wr * WM + mi * 16 + fq * 4;
#pragma unroll
            for (int ni = 0; ni < 4; ++ni) {
                const int col = n0 + wc * 64 + ni * 16 + fr;
                f32x4 a = acc[mi][ni];
                if (CMODE != CM_F32) {
                    const float bv = bias[col];
#pragma unroll
                    for (int j = 0; j < 4; ++j) a[j] += bv;
                }
                if (CMODE == CM_F32) {
                    float* C = (float*)C1 + (long)z * sCz;
#pragma unroll
                    for (int j = 0; j < 4; ++j)
                        C[(long)(rbase + j) * ldc + col] = a[j];
                } else {  // CM_F16
                    _Float16* Ch = (_Float16*)C1;
#pragma unroll
                    for (int j = 0; j < 4; ++j)
                        Ch[(long)(rbase + j) * ldc + col] = (_Float16)a[j];
                }
            }
        }
    }
}

// ---------------------------------------------------------------------------
// X -> single fp16 plane.
__global__ __launch_bounds__(256) void xsplit(
    const float* __restrict__ X, _Float16* __restrict__ Xh)
{
    const long i = ((long)blockIdx.x * 256 + threadIdx.x) * 8;
    f32x4 v0 = *(const f32x4*)(X + i);
    f32x4 v1 = *(const f32x4*)(X + i + 4);
    f16x8 h;
#pragma unroll
    for (int j = 0; j < 4; ++j) { h[j] = (_Float16)v0[j]; h[4 + j] = (_Float16)v1[j]; }
    *(f16x8*)(Xh + i) = h;
}

// ---------------------------------------------------------------------------
// Transpose 1024x1024 W -> single f16 plane (1-term projections).
__global__ void wsplit(const float* __restrict__ W0, const float* __restrict__ W1,
                       const float* __restrict__ W2, _Float16* __restrict__ Th)
{
    const float* W = blockIdx.z == 0 ? W0 : (blockIdx.z == 1 ? W1 : W2);
    _Float16* th = Th + (long)blockIdx.z * 1024 * 1024;
    __shared__ float tile[32][33];
    const int bx = blockIdx.x * 32, by = blockIdx.y * 32;
    const int tx = threadIdx.x, ty = threadIdx.y;
#pragma unroll
    for (int i = ty; i < 32; i += 8) tile[i][tx] = W[(long)(by + i) * 1024 + bx + tx];
    __syncthreads();
#pragma unroll
    for (int i = ty; i < 32; i += 8)
        th[(long)(bx + i) * 1024 + by + tx] = (_Float16)tile[tx][i];
}

// ---------------------------------------------------------------------------
// Fused row softmax: f32 score row -> P = exp(s-m)/l as fp16, in-place.
__global__ __launch_bounds__(256) void pconv(float* __restrict__ Sb)
{
    const long row = blockIdx.x;
    float* p = Sb + row * (long)S;
    const int t = threadIdx.x;

    f32x4 x0 = *(const f32x4*)(p + t * 8);
    f32x4 x1 = *(const f32x4*)(p + t * 8 + 4);

    float m = -3.4e38f;
#pragma unroll
    for (int j = 0; j < 4; ++j) m = fmaxf(m, fmaxf(x0[j], x1[j]));
#pragma unroll
    for (int o = 32; o >= 1; o >>= 1) m = fmaxf(m, __shfl_xor(m, o));

    __shared__ float wm[4], wsum[4];
    const int wid = t >> 6, lane = t & 63;
    if (lane == 0) wm[wid] = m;
    __syncthreads();
    m = fmaxf(fmaxf(wm[0], wm[1]), fmaxf(wm[2], wm[3]));

    float e[8], ssum = 0.f;
#pragma unroll
    for (int j = 0; j < 4; ++j) {
        e[j]     = exp2f((x0[j] - m) * LOG2E);
        e[4 + j] = exp2f((x1[j] - m) * LOG2E);
        ssum += e[j] + e[4 + j];
    }
#pragma unroll
    for (int o = 32; o >= 1; o >>= 1) ssum += __shfl_xor(ssum, o);
    if (lane == 0) wsum[wid] = ssum;
    __syncthreads();
    const float invl = 1.0f / (wsum[0] + wsum[1] + wsum[2] + wsum[3]);

    f16x8 outv;
#pragma unroll
    for (int j = 0; j < 8; ++j) outv[j] = (_Float16)(e[j] * invl);
    *(f16x8*)((_Float16*)p + t * 8) = outv;
}

// ---------------------------------------------------------------------------
extern "C" void kernel_launch(void* const* d_in, const int* in_sizes, int n_in,
                              void* d_out, int out_size, void* d_ws, size_t ws_size,
                              hipStream_t stream)
{
    const float* X  = (const float*)d_in[0];
    const float* Wq = (const float*)d_in[1];
    const float* bq = (const float*)d_in[2];
    const float* Wk = (const float*)d_in[3];
    const float* bk = (const float*)d_in[4];
    const float* Wv = (const float*)d_in[5];
    const float* bv = (const float*)d_in[6];
    float* out = (float*)d_out;
    char* ws = (char*)d_ws;
    const size_t MB = 1u << 20;

    // layout (230 MB): [0,6) Wh[3] f16  [6,38) Qh f16  [38,70) Kh f16
    // [70,102) Vt f16  [102,230) Sb f32 [8][S][S] (P f16 in-place)
    // Xh (32 MB f16) aliases Sb's first part [102,134) — dead before scores.
    _Float16* Wh = (_Float16*)ws;
    _Float16* Qh = (_Float16*)(ws + 6 * MB);
    _Float16* Kh = (_Float16*)(ws + 38 * MB);
    _Float16* Vt = (_Float16*)(ws + 70 * MB);
    float*    Sb = (float*)(ws + 102 * MB);
    _Float16* Xh = (_Float16*)(ws + 102 * MB);

    const int LDS_T1 = 98304;
    hipFuncSetAttribute(reinterpret_cast<const void*>(&bgemm256<CM_F16>),
                        hipFuncAttributeMaxDynamicSharedMemorySize, LDS_T1);
    hipFuncSetAttribute(reinterpret_cast<const void*>(&bgemm256<CM_TRANSV>),
                        hipFuncAttributeMaxDynamicSharedMemorySize, LDS_T1);
    hipFuncSetAttribute(reinterpret_cast<const void*>(&bgemm256<CM_F32>),
                        hipFuncAttributeMaxDynamicSharedMemorySize, LDS_T1);

    // 1) convert X -> f16 single plane; W -> f16 single plane (transposed)
    xsplit<<<dim3(8192), 256, 0, stream>>>(X, Xh);
    wsplit<<<dim3(32, 32, 3), dim3(32, 8), 0, stream>>>(Wq, Wk, Wv, Wh);

    // 2) projections: 1-term fp16 (Xh * Wh); Q,K single f16; V -> Vt f16.
    const long MW = 1024 * 1024;
    bgemm256<CM_F16><<<dim3(D / 128, 64, 1), 512, LDS_T1, stream>>>(
        Xh, 0, Wh, 0, D, D, Qh, D, 0, bq, D);
    bgemm256<CM_F16><<<dim3(D / 128, 64, 1), 512, LDS_T1, stream>>>(
        Xh, 0, Wh + MW, 0, D, D, Kh, D, 0, bk, D);
    bgemm256<CM_TRANSV><<<dim3(D / 128, 64, 1), 512, LDS_T1, stream>>>(
        Xh, 0, Wh + 2 * MW, 0, D, D, Vt, 0, 0, bv, D);

    // 3) single pass, all 8 batches: scores -> softmax->f16 P -> PV
    bgemm256<CM_F32><<<dim3(S / 128, S / 256, NB), 512, LDS_T1, stream>>>(
        Qh, (long)S * D, Kh, (long)S * D,
        D, D, Sb, S, (long)S * S, nullptr, D);
    pconv<<<dim3(NB * S), 256, 0, stream>>>(Sb);
    // PV: A = f16 P rows embedded in f32 buffer (lda = 2S f16 elements)
    bgemm256<CM_F32><<<dim3(D / 128, S / 256, NB), 512, LDS_T1, stream>>>(
        (const _Float16*)Sb, 2L * S * S, Vt, (long)D * S,
        2 * S, S, out, D, (long)S * D, nullptr, S);
}